// Round 2
// baseline (1135.922 us; speedup 1.0000x reference)
//
#include <hip/hip_runtime.h>
#include <hip/hip_bf16.h>

typedef __hip_bfloat16 bf16;

#define CSD    384
#define LL     1024
#define NH     8
#define BL     4096        // B*L
#define NPROJ  1920
#define QDP    96          // 80 real ext-Q/K dims, padded to 96 (8 lanes x 12)
#define VDP    160         // 152 real ext-V dims, padded to 160 (8 lanes x 20)
#define FEATD  1280

// ---- fp32 input mirror layout (float offsets inside d_ws) ----
#define OFF_S      0
#define OFF_Z1     1572864
#define OFF_Z2     2621440
#define OFF_QUAT   4718592
#define OFF_TRANS  4734976
#define OFF_MASK   4747264
#define OFF_BPOST  4751360
#define OFF_BRES   4751376
#define OFF_WPOST  4751392
#define OFF_WRES   4757536
#define OFF_ALPHA  4782112
#define OFF_WQ     4782128
#define OFF_WK     4978736
#define OFF_WV     5175344
#define OFF_WQP    5371952
#define OFF_WKP    5408816
#define OFF_WVP    5445680
#define OFF_WZQ    5519408
#define OFF_WZK    5520432
#define OFF_HEADW  5521456
#define OFF_WO     5521472
#define OFF_BO     6012992
#define OFF_LN1G   6013376
#define OFF_LN1B   6013760
#define OFF_WT1    6014144
#define OFF_BT1    6161600
#define OFF_WT2    6161984
#define OFF_BT2    6309440
#define OFF_WT3    6309824
#define OFF_BT3    6457280
#define OFF_LNTG   6457664
#define OFF_LNTB   6458048
#define OFF_WBB    6458432
#define OFF_BBB    6460736
#define IN_END     6460752

// ---- scratch layout after the mirror ----
#define WS_FLAG    6460752
#define WS_WPOSTR  6460768      // 1,536
#define WS_WRESR   6462304      // 6,144
#define WS_HPOST   6468448      // 16,384
#define WS_ROWSUM  6484832      // 16,384
#define WS_ROTB    6501216      // 36,864
#define WS_WCAT    6538080      // 737,280 fp32 concat weights [384,1920]
#define WS_PROJ    7275360      // 7,864,320 ; overlays: Oext (5,242,880), later x3
#define WS_QEXT    15139680     // 3,145,728 ; overlays: feat (spans into KEXT), later sipa
#define WS_KEXT    18285408     // 3,145,728
#define WS_VEXT    21431136     // 5,242,880 ; overlays: x1/s1, t1, t2
// end: 26,674,016 floats = 106.7 MB

#define OUT_ROT 6291456
#define OUT_TR  6328320

#define NSEG 34

struct P36 { const void* p[36]; };

__device__ __forceinline__ float b2f(bf16 x) { return __bfloat162float(x); }

__device__ __forceinline__ float wredf(float v) {
#pragma unroll
  for (int o = 1; o < 64; o <<= 1) v += __shfl_xor(v, o, 64);
  return v;
}

// ---------- dtype detect: mask is all-ones; bf16 pair = 0x3F803F80, fp32 = 0x3F800000 ----------
__global__ void detect_k(const unsigned int* __restrict__ mask_raw, int* __restrict__ flag) {
  if (threadIdx.x == 0 && blockIdx.x == 0) flag[0] = (mask_raw[0] == 0x3F803F80u) ? 1 : 0;
}

// ---------- convert ALL inputs into contiguous fp32 mirror ----------
__global__ __launch_bounds__(256) void cvtall_k(P36 ptrs, float* __restrict__ dst, const int* __restrict__ flagp) {
  const int i = blockIdx.x * 256 + threadIdx.x;
  if (i >= IN_END) return;
  const int flag = flagp[0];
  // segment tables (compile-time constants after unroll)
  const int seg_src_t[NSEG] = {0,1,2,3,4,5,7,8,10,11,12,13,14,15,16,17,18,19,20,21,22,23,24,25,26,27,28,29,30,31,32,33,34,35};
  const int seg_dst_t[NSEG] = {OFF_S,OFF_Z1,OFF_Z2,OFF_QUAT,OFF_TRANS,OFF_MASK,OFF_BPOST,OFF_BRES,OFF_WPOST,OFF_WRES,
                               OFF_ALPHA,OFF_WQ,OFF_WK,OFF_WV,OFF_WQP,OFF_WKP,OFF_WVP,OFF_WZQ,OFF_WZK,OFF_HEADW,
                               OFF_WO,OFF_BO,OFF_LN1G,OFF_LN1B,OFF_WT1,OFF_BT1,OFF_WT2,OFF_BT2,OFF_WT3,OFF_BT3,
                               OFF_LNTG,OFF_LNTB,OFF_WBB,OFF_BBB};
  const int seg_cnt_t[NSEG] = {1572864,1048576,2097152,16384,12288,4096,4,16,6144,24576,
                               1,196608,196608,196608,36864,36864,73728,1024,1024,8,
                               491520,384,384,384,147456,384,147456,384,147456,384,
                               384,384,2304,6};
  int off = i, cnt = seg_cnt_t[0];
  const void* sp = ptrs.p[0];
#pragma unroll
  for (int k = 1; k < NSEG; k++) {
    if (i >= seg_dst_t[k]) { off = i - seg_dst_t[k]; cnt = seg_cnt_t[k]; sp = ptrs.p[seg_src_t[k]]; }
  }
  float v = 0.f;
  if (off < cnt) {
    v = flag ? b2f(((const bf16*)sp)[off]) : ((const float*)sp)[off];
  }
  dst[i] = v;
}

// ---------- concat projection weights into fp32 [384,1920] ----------
__global__ __launch_bounds__(256) void concat_k(const float* __restrict__ Wq, const float* __restrict__ Wk,
                                                const float* __restrict__ Wv, const float* __restrict__ Wqp,
                                                const float* __restrict__ Wkp, const float* __restrict__ Wvp,
                                                float* __restrict__ Wcat) {
  int i = blockIdx.x * 256 + threadIdx.x;
  if (i >= CSD * NPROJ) return;
  int k = i / NPROJ, c = i % NPROJ;
  float v;
  if (c < 512)       v = Wq[k * 512 + c];
  else if (c < 1024) v = Wk[k * 512 + c - 512];
  else if (c < 1536) v = Wv[k * 512 + c - 1024];
  else if (c < 1632) v = Wqp[k * 96 + c - 1536];
  else if (c < 1728) v = Wkp[k * 96 + c - 1632];
  else               v = Wvp[k * 192 + c - 1728];
  Wcat[i] = v;
}

// ---------- reduce W_post [1536,4]->[384,4], W_res [1536,16]->[384,16] ----------
__global__ __launch_bounds__(256) void wreduce_k(const float* __restrict__ Wpost, const float* __restrict__ Wres,
                                                 float* __restrict__ WpostR, float* __restrict__ WresR) {
  int i = blockIdx.x * 256 + threadIdx.x;
  if (i < CSD * 4) {
    int c = i >> 2, n = i & 3;
    float s = 0.f;
#pragma unroll
    for (int blk = 0; blk < 4; blk++) s += Wpost[(blk * CSD + c) * 4 + n];
    WpostR[i] = s;
  }
  if (i < CSD * 16) {
    int c = i >> 4, n = i & 15;
    float s = 0.f;
#pragma unroll
    for (int blk = 0; blk < 4; blk++) s += Wres[(blk * CSD + c) * 16 + n];
    WresR[i] = s;
  }
}

// ---------- per-residue: H_post, sinkhorn row-sums, quat->rot ----------
__global__ __launch_bounds__(64) void mhc_k(const float* __restrict__ sF, const float* __restrict__ quat,
                                            const float* __restrict__ bpost, const float* __restrict__ bres,
                                            const float* __restrict__ alpha_p, const float* __restrict__ WpostR,
                                            const float* __restrict__ WresR, float* __restrict__ hpost,
                                            float* __restrict__ rowsum, float* __restrict__ rotb) {
  const int bl = blockIdx.x, t = threadIdx.x;
  const float* sr = sF + (size_t)bl * CSD;
  float ssq = 0.f, dp[4] = {0.f, 0.f, 0.f, 0.f}, dr[16];
#pragma unroll
  for (int n = 0; n < 16; n++) dr[n] = 0.f;
#pragma unroll
  for (int e = 0; e < 6; e++) {
    const int c = t + e * 64;
    const float sv = sr[c];
    ssq = fmaf(sv, sv, ssq);
#pragma unroll
    for (int n = 0; n < 4; n++) dp[n] = fmaf(sv, WpostR[c * 4 + n], dp[n]);
#pragma unroll
    for (int n = 0; n < 16; n++) dr[n] = fmaf(sv, WresR[c * 16 + n], dr[n]);
  }
  ssq = wredf(ssq);
#pragma unroll
  for (int n = 0; n < 4; n++) dp[n] = wredf(dp[n]);
#pragma unroll
  for (int n = 0; n < 16; n++) dr[n] = wredf(dr[n]);
  const float alpha = alpha_p[0];
  const float invn = rsqrtf(ssq * (1.f / 384.f) + 1e-6f);  // rms of replicated h == rms of s
  if (t == 0) {
#pragma unroll
    for (int n = 0; n < 4; n++) {
      const float x = bpost[n] + alpha * invn * dp[n];
      hpost[bl * 4 + n] = 2.f / (1.f + __expf(-x));
    }
    float M[16];
    float mx = -1e30f;
#pragma unroll
    for (int k = 0; k < 16; k++) { M[k] = bres[k] + alpha * invn * dr[k]; mx = fmaxf(mx, M[k]); }
#pragma unroll
    for (int k = 0; k < 16; k++) M[k] = __expf(M[k] - mx);
    for (int it = 0; it < 20; it++) {
#pragma unroll
      for (int r = 0; r < 4; r++) {
        const float s4 = M[r * 4] + M[r * 4 + 1] + M[r * 4 + 2] + M[r * 4 + 3];
        const float iv = 1.f / (s4 + 1e-8f);
        M[r * 4] *= iv; M[r * 4 + 1] *= iv; M[r * 4 + 2] *= iv; M[r * 4 + 3] *= iv;
      }
#pragma unroll
      for (int c2 = 0; c2 < 4; c2++) {
        const float s4 = M[c2] + M[4 + c2] + M[8 + c2] + M[12 + c2];
        const float iv = 1.f / (s4 + 1e-8f);
        M[c2] *= iv; M[4 + c2] *= iv; M[8 + c2] *= iv; M[12 + c2] *= iv;
      }
    }
#pragma unroll
    for (int r = 0; r < 4; r++)
      rowsum[bl * 4 + r] = M[r * 4] + M[r * 4 + 1] + M[r * 4 + 2] + M[r * 4 + 3];
  }
  if (t == 1) {
    float w = quat[bl * 4 + 0], x = quat[bl * 4 + 1];
    float y = quat[bl * 4 + 2], z = quat[bl * 4 + 3];
    const float iq = rsqrtf(w * w + x * x + y * y + z * z + 1e-8f);
    w *= iq; x *= iq; y *= iq; z *= iq;
    float* R = rotb + (size_t)bl * 9;
    R[0] = 1.f - 2.f * (y * y + z * z); R[1] = 2.f * (x * y - w * z); R[2] = 2.f * (x * z + w * y);
    R[3] = 2.f * (x * y + w * z); R[4] = 1.f - 2.f * (x * x + z * z); R[5] = 2.f * (y * z - w * x);
    R[6] = 2.f * (x * z - w * y); R[7] = 2.f * (y * z + w * x); R[8] = 1.f - 2.f * (x * x + y * y);
  }
}

// ---------- generic fp32 tiled GEMM: C[M,N] = A[M,K] @ B[K,N] (+bias)(+relu) ----------
__global__ __launch_bounds__(256) void gemm_k(const float* __restrict__ A, const float* __restrict__ Bw,
                                              const float* __restrict__ bias, float* __restrict__ C,
                                              int M, int N, int K, int relu) {
  __shared__ __align__(16) float As[16][68];
  __shared__ __align__(16) float Bs[16][68];
  const int tid = threadIdx.x;
  const int tx = tid & 15, ty = tid >> 4;
  const int bm = blockIdx.y, bn = blockIdx.x;
  const float* Ab = A + (size_t)bm * 64 * K;
  const float* Bb = Bw + bn * 64;
  float acc[4][4];
#pragma unroll
  for (int i = 0; i < 4; i++)
#pragma unroll
    for (int j = 0; j < 4; j++) acc[i][j] = 0.f;
  for (int k0 = 0; k0 < K; k0 += 16) {
#pragma unroll
    for (int e = 0; e < 4; e++) {
      const int idx = tid + e * 256;
      const int m = idx >> 4, kk = idx & 15;
      As[kk][m] = Ab[(size_t)m * K + k0 + kk];
    }
#pragma unroll
    for (int e = 0; e < 4; e++) {
      const int idx = tid + e * 256;
      const int kk = idx >> 6, n = idx & 63;
      Bs[kk][n] = Bb[(size_t)(k0 + kk) * N + n];
    }
    __syncthreads();
#pragma unroll
    for (int kk = 0; kk < 16; kk++) {
      const float4 a4 = *(const float4*)&As[kk][ty * 4];
      const float4 b4 = *(const float4*)&Bs[kk][tx * 4];
      const float av[4] = {a4.x, a4.y, a4.z, a4.w};
      const float bv[4] = {b4.x, b4.y, b4.z, b4.w};
#pragma unroll
      for (int i = 0; i < 4; i++)
#pragma unroll
        for (int j = 0; j < 4; j++) acc[i][j] = fmaf(av[i], bv[j], acc[i][j]);
    }
    __syncthreads();
  }
#pragma unroll
  for (int i = 0; i < 4; i++) {
    const int m = bm * 64 + ty * 4 + i;
#pragma unroll
    for (int j = 0; j < 4; j++) {
      const int n = bn * 64 + tx * 4 + j;
      float v = acc[i][j];
      if (bias != nullptr) v += bias[n];
      if (relu) v = fmaxf(v, 0.f);
      C[(size_t)m * N + n] = v;
    }
  }
}

// ---------- assemble extended Q/K/V (one thread per (b,l,h)) ----------
__global__ __launch_bounds__(256) void assemble_k(const float* __restrict__ proj, const float* __restrict__ rotb,
                                                  const float* __restrict__ trans, const float* __restrict__ z1,
                                                  const float* __restrict__ z2, const float* __restrict__ Wzq,
                                                  const float* __restrict__ Wzk, const float* __restrict__ headw,
                                                  float* __restrict__ Qext, float* __restrict__ Kext,
                                                  float* __restrict__ Vext) {
  const int idx = blockIdx.x * 256 + threadIdx.x;  // < 32768
  const int h = idx & 7, bl = idx >> 3;
  const float* pr = proj + (size_t)bl * NPROJ;
  const float* R = rotb + (size_t)bl * 9;
  const float txx = trans[bl * 3 + 0], tyy = trans[bl * 3 + 1], tzz = trans[bl * 3 + 2];
  float gamma;
  { const float w = headw[h]; gamma = (w > 20.f) ? w : log1pf(__expf(w)); }
  const float wL = 0.57735026918962576f;  // sqrt(1/3)
  const float wC = 0.23570226039551584f;  // sqrt(2/(9*4))
  const float ch = wL * wC * 0.5f * gamma;
  const float qscale = wL * 0.125f;       // wL / sqrt(64)

  float zq0 = 0.f, zq1 = 0.f, zk0 = 0.f, zk1 = 0.f;
  const float* z1r = z1 + (size_t)bl * 256;
  for (int zz = 0; zz < 128; zz++) {
    const float wq = Wzq[zz * 8 + h], wk = Wzk[zz * 8 + h];
    const float a0 = z1r[zz], a1 = z1r[128 + zz];
    zq0 = fmaf(a0, wq, zq0); zq1 = fmaf(a1, wq, zq1);
    zk0 = fmaf(a0, wk, zk0); zk1 = fmaf(a1, wk, zk1);
  }
  const int b = bl >> 10, l = bl & 1023;
  const size_t row = (size_t)(b * NH + h) * LL + l;
  float* Q = Qext + row * QDP;
  float* Kx = Kext + row * QDP;
  float* V = Vext + row * VDP;
  for (int c = 0; c < 64; c++) { Q[c] = pr[h * 64 + c] * qscale; Kx[c] = pr[512 + h * 64 + c]; }
  Q[64] = wL * zq0; Q[65] = wL * zq1;
  Kx[64] = zk0; Kx[65] = zk1;
  float qn = 0.f, kn = 0.f;
#pragma unroll
  for (int p = 0; p < 4; p++) {
    const float* pl = pr + 1536 + h * 12 + p * 3;
    float gx = R[0] * pl[0] + R[1] * pl[1] + R[2] * pl[2] + txx;
    float gy = R[3] * pl[0] + R[4] * pl[1] + R[5] * pl[2] + tyy;
    float gz = R[6] * pl[0] + R[7] * pl[1] + R[8] * pl[2] + tzz;
    qn += gx * gx + gy * gy + gz * gz;
    Q[66 + p * 3 + 0] = 2.f * ch * gx; Q[66 + p * 3 + 1] = 2.f * ch * gy; Q[66 + p * 3 + 2] = 2.f * ch * gz;
    const float* pk = pr + 1632 + h * 12 + p * 3;
    gx = R[0] * pk[0] + R[1] * pk[1] + R[2] * pk[2] + txx;
    gy = R[3] * pk[0] + R[4] * pk[1] + R[5] * pk[2] + tyy;
    gz = R[6] * pk[0] + R[7] * pk[1] + R[8] * pk[2] + tzz;
    kn += gx * gx + gy * gy + gz * gz;
    Kx[66 + p * 3 + 0] = gx; Kx[66 + p * 3 + 1] = gy; Kx[66 + p * 3 + 2] = gz;
  }
  Q[78] = -ch * qn; Q[79] = 1.f;
  Kx[78] = 1.f;     Kx[79] = -ch * kn;
  for (int c = 80; c < QDP; c++) { Q[c] = 0.f; Kx[c] = 0.f; }
  for (int c = 0; c < 64; c++) V[c] = pr[1024 + h * 64 + c];
#pragma unroll
  for (int p = 0; p < 8; p++) {
    const float* pv = pr + 1728 + h * 24 + p * 3;
    const float gx = R[0] * pv[0] + R[1] * pv[1] + R[2] * pv[2] + txx;
    const float gy = R[3] * pv[0] + R[4] * pv[1] + R[5] * pv[2] + tyy;
    const float gz = R[6] * pv[0] + R[7] * pv[1] + R[8] * pv[2] + tzz;
    V[64 + p * 3 + 0] = gx; V[64 + p * 3 + 1] = gy; V[64 + p * 3 + 2] = gz;
  }
  const float* z2r = z2 + ((size_t)bl * NH + h) * 64;
  for (int c = 0; c < 64; c++) V[88 + c] = z2r[c];
  for (int c = 152; c < VDP; c++) V[c] = 0.f;
}

// ---------- flash attention over folded 80-dim logits / 152-dim values ----------
__global__ __launch_bounds__(256) void attn_k(const float* __restrict__ Qext, const float* __restrict__ Kext,
                                              const float* __restrict__ Vext, const float* __restrict__ mask,
                                              float* __restrict__ Oext) {
  __shared__ __align__(16) float Ks[32 * QDP];
  __shared__ __align__(16) float Vs[32 * VDP];
  __shared__ float Ms[32];
  const int tid = threadIdx.x;
  const int g = tid >> 3, sub = tid & 7;
  const int bh = blockIdx.y;
  const int b = bh >> 3, h = bh & 7;
  const int i = blockIdx.x * 32 + g;

  const float* Qr = Qext + ((size_t)bh * LL + i) * QDP + sub * 12;
  const float4 q0 = *(const float4*)(Qr + 0);
  const float4 q1 = *(const float4*)(Qr + 4);
  const float4 q2 = *(const float4*)(Qr + 8);

  float m = -1e30f, lsum = 0.f;
  float acc[20];
#pragma unroll
  for (int t = 0; t < 20; t++) acc[t] = 0.f;

  const float4* Kb = (const float4*)(Kext + (size_t)bh * LL * QDP);
  const float4* Vb = (const float4*)(Vext + (size_t)bh * LL * VDP);
  float4* Ks4 = (float4*)Ks;
  float4* Vs4 = (float4*)Vs;
  const float* mr = mask + b * LL;

  for (int jt = 0; jt < 32; jt++) {
    const int j0 = jt * 32;
    __syncthreads();
#pragma unroll
    for (int e = 0; e < 3; e++) Ks4[tid + e * 256] = Kb[j0 * 24 + tid + e * 256];
#pragma unroll
    for (int e = 0; e < 5; e++) Vs4[tid + e * 256] = Vb[j0 * 40 + tid + e * 256];
    if (tid < 32) Ms[tid] = mr[j0 + tid];
    __syncthreads();

    float lg[32];
#pragma unroll
    for (int j = 0; j < 32; j++) {
      const float4* kr = (const float4*)(Ks + j * QDP + sub * 12);
      const float4 k0 = kr[0], k1 = kr[1], k2 = kr[2];
      lg[j] = q0.x * k0.x + q0.y * k0.y + q0.z * k0.z + q0.w * k0.w
            + q1.x * k1.x + q1.y * k1.y + q1.z * k1.z + q1.w * k1.w
            + q2.x * k2.x + q2.y * k2.y + q2.z * k2.z + q2.w * k2.w;
    }
#pragma unroll
    for (int j = 0; j < 32; j++) {
      float p = lg[j];
      p += __shfl_xor(p, 1, 64);
      p += __shfl_xor(p, 2, 64);
      p += __shfl_xor(p, 4, 64);
      lg[j] = (Ms[j] > 0.f) ? p : -1e9f;
    }
    float tm = lg[0];
#pragma unroll
    for (int j = 1; j < 32; j++) tm = fmaxf(tm, lg[j]);
    const float mn = fmaxf(m, tm);
    const float sc = __expf(m - mn);
    m = mn;
    lsum *= sc;
#pragma unroll
    for (int t = 0; t < 20; t++) acc[t] *= sc;
#pragma unroll
    for (int j = 0; j < 32; j++) {
      const float p = __expf(lg[j] - mn);
      lsum += p;
      const float4* vr = (const float4*)(Vs + j * VDP + sub * 20);
      const float4 v0 = vr[0], v1 = vr[1], v2 = vr[2], v3 = vr[3], v4 = vr[4];
      acc[0]  = fmaf(p, v0.x, acc[0]);  acc[1]  = fmaf(p, v0.y, acc[1]);
      acc[2]  = fmaf(p, v0.z, acc[2]);  acc[3]  = fmaf(p, v0.w, acc[3]);
      acc[4]  = fmaf(p, v1.x, acc[4]);  acc[5]  = fmaf(p, v1.y, acc[5]);
      acc[6]  = fmaf(p, v1.z, acc[6]);  acc[7]  = fmaf(p, v1.w, acc[7]);
      acc[8]  = fmaf(p, v2.x, acc[8]);  acc[9]  = fmaf(p, v2.y, acc[9]);
      acc[10] = fmaf(p, v2.z, acc[10]); acc[11] = fmaf(p, v2.w, acc[11]);
      acc[12] = fmaf(p, v3.x, acc[12]); acc[13] = fmaf(p, v3.y, acc[13]);
      acc[14] = fmaf(p, v3.z, acc[14]); acc[15] = fmaf(p, v3.w, acc[15]);
      acc[16] = fmaf(p, v4.x, acc[16]); acc[17] = fmaf(p, v4.y, acc[17]);
      acc[18] = fmaf(p, v4.z, acc[18]); acc[19] = fmaf(p, v4.w, acc[19]);
    }
  }
  const float inv = 1.f / lsum;
  float4* Or = (float4*)(Oext + ((size_t)(b * LL + i) * NH + h) * VDP + sub * 20);
  Or[0] = make_float4(acc[0] * inv, acc[1] * inv, acc[2] * inv, acc[3] * inv);
  Or[1] = make_float4(acc[4] * inv, acc[5] * inv, acc[6] * inv, acc[7] * inv);
  Or[2] = make_float4(acc[8] * inv, acc[9] * inv, acc[10] * inv, acc[11] * inv);
  Or[3] = make_float4(acc[12] * inv, acc[13] * inv, acc[14] * inv, acc[15] * inv);
  Or[4] = make_float4(acc[16] * inv, acc[17] * inv, acc[18] * inv, acc[19] * inv);
}

// ---------- feat assembly: local-frame transform + norms (thread per (b,l,h)) ----------
__global__ __launch_bounds__(256) void feat_k(const float* __restrict__ Oext, const float* __restrict__ rotb,
                                              const float* __restrict__ trans, float* __restrict__ feat) {
  const int idx = blockIdx.x * 256 + threadIdx.x;
  const int h = idx & 7, bl = idx >> 3;
  const float* O = Oext + (size_t)(bl * 8 + h) * VDP;
  float* f = feat + (size_t)bl * FEATD;
  for (int c = 0; c < 64; c++) f[h * 64 + c] = O[c];
  const float* R = rotb + (size_t)bl * 9;
  const float txx = trans[bl * 3 + 0], tyy = trans[bl * 3 + 1], tzz = trans[bl * 3 + 2];
#pragma unroll
  for (int p = 0; p < 8; p++) {
    const float dx = O[64 + p * 3 + 0] - txx;
    const float dy = O[64 + p * 3 + 1] - tyy;
    const float dz = O[64 + p * 3 + 2] - tzz;
    const float lx = R[0] * dx + R[3] * dy + R[6] * dz;   // R^T * diff
    const float ly = R[1] * dx + R[4] * dy + R[7] * dz;
    const float lz = R[2] * dx + R[5] * dy + R[8] * dz;
    f[512 + h * 24 + p * 3 + 0] = lx;
    f[512 + h * 24 + p * 3 + 1] = ly;
    f[512 + h * 24 + p * 3 + 2] = lz;
    f[704 + h * 8 + p] = sqrtf(lx * lx + ly * ly + lz * lz + 1e-8f);
  }
  for (int c = 0; c < 64; c++) f[768 + h * 64 + c] = O[88 + c];
}

// ---------- LayerNorm(x + resid) (one wave per row) ----------
__global__ __launch_bounds__(64) void ln_k(const float* __restrict__ x, const float* __restrict__ resid,
                                           const float* __restrict__ g, const float* __restrict__ bta,
                                           float* __restrict__ out) {
  const int row = blockIdx.x, t = threadIdx.x;
  const float* xr = x + (size_t)row * CSD;
  const float* rr = resid + (size_t)row * CSD;
  float v[6];
  float s = 0.f;
#pragma unroll
  for (int e = 0; e < 6; e++) {
    const int c = t + e * 64;
    v[e] = xr[c] + rr[c];
    s += v[e];
  }
  s = wredf(s);
  const float mu = s * (1.f / 384.f);
  float var = 0.f;
#pragma unroll
  for (int e = 0; e < 6; e++) { const float d = v[e] - mu; var = fmaf(d, d, var); }
  var = wredf(var) * (1.f / 384.f);
  const float inv = rsqrtf(var + 1e-5f);
#pragma unroll
  for (int e = 0; e < 6; e++) {
    const int c = t + e * 64;
    out[(size_t)row * CSD + c] = (v[e] - mu) * inv * g[c] + bta[c];
  }
}

// ---------- final: backbone update + mHC combine; writes output per dtype flag ----------
__global__ __launch_bounds__(64) void final_k(const float* __restrict__ sF, const float* __restrict__ sipa,
                                              const float* __restrict__ rotb, const float* __restrict__ trans,
                                              const float* __restrict__ hpost, const float* __restrict__ rowsum,
                                              const float* __restrict__ Wbb, const float* __restrict__ bbb,
                                              const int* __restrict__ flagp, void* __restrict__ outv) {
  const int bl = blockIdx.x, t = threadIdx.x;
  const int flag = flagp[0];
  bf16* outb = (bf16*)outv;
  float* outf = (float*)outv;
  const float* si = sipa + (size_t)bl * CSD;
  float d6[6] = {0.f, 0.f, 0.f, 0.f, 0.f, 0.f};
#pragma unroll
  for (int e = 0; e < 6; e++) {
    const int c = t + e * 64;
    const float v = si[c];
#pragma unroll
    for (int u = 0; u < 6; u++) d6[u] = fmaf(v, Wbb[c * 6 + u], d6[u]);
  }
#pragma unroll
  for (int u = 0; u < 6; u++) d6[u] = wredf(d6[u]);
  float upd[6];
#pragma unroll
  for (int u = 0; u < 6; u++) upd[u] = d6[u] + bbb[u];
  const float* R = rotb + (size_t)bl * 9;
  if (t == 0) {
    float w = 1.f, x = upd[0], y = upd[1], z = upd[2];
    const float iq = rsqrtf(w * w + x * x + y * y + z * z + 1e-8f);
    w *= iq; x *= iq; y *= iq; z *= iq;
    const float Ru[9] = {1.f - 2.f * (y * y + z * z), 2.f * (x * y - w * z), 2.f * (x * z + w * y),
                         2.f * (x * y + w * z), 1.f - 2.f * (x * x + z * z), 2.f * (y * z - w * x),
                         2.f * (x * z - w * y), 2.f * (y * z + w * x), 1.f - 2.f * (x * x + y * y)};
#pragma unroll
    for (int i = 0; i < 3; i++)
#pragma unroll
      for (int j = 0; j < 3; j++) {
        const float rv = R[i * 3 + 0] * Ru[0 + j] + R[i * 3 + 1] * Ru[3 + j] + R[i * 3 + 2] * Ru[6 + j];
        const size_t o = OUT_ROT + (size_t)bl * 9 + i * 3 + j;
        if (flag) outb[o] = __float2bfloat16(rv); else outf[o] = rv;
      }
#pragma unroll
    for (int i = 0; i < 3; i++) {
      const float tv = R[i * 3 + 0] * upd[3] + R[i * 3 + 1] * upd[4] + R[i * 3 + 2] * upd[5] + trans[bl * 3 + i];
      const size_t o = OUT_TR + (size_t)bl * 3 + i;
      if (flag) outb[o] = __float2bfloat16(tv); else outf[o] = tv;
    }
  }
  const float hp0 = hpost[bl * 4 + 0], hp1 = hpost[bl * 4 + 1], hp2 = hpost[bl * 4 + 2], hp3 = hpost[bl * 4 + 3];
  const float rs0 = rowsum[bl * 4 + 0], rs1 = rowsum[bl * 4 + 1], rs2 = rowsum[bl * 4 + 2], rs3 = rowsum[bl * 4 + 3];
  const float* sr = sF + (size_t)bl * CSD;
#pragma unroll
  for (int e = 0; e < 6; e++) {
    const int c = t + e * 64;
    const float sv = sr[c], sp = si[c];
    const size_t base = (size_t)bl * 4 * CSD + c;
    const float o0 = rs0 * sv + hp0 * sp;
    const float o1 = rs1 * sv + hp1 * sp;
    const float o2 = rs2 * sv + hp2 * sp;
    const float o3 = rs3 * sv + hp3 * sp;
    if (flag) {
      outb[base + 0 * CSD] = __float2bfloat16(o0);
      outb[base + 1 * CSD] = __float2bfloat16(o1);
      outb[base + 2 * CSD] = __float2bfloat16(o2);
      outb[base + 3 * CSD] = __float2bfloat16(o3);
    } else {
      outf[base + 0 * CSD] = o0;
      outf[base + 1 * CSD] = o1;
      outf[base + 2 * CSD] = o2;
      outf[base + 3 * CSD] = o3;
    }
  }
}

extern "C" void kernel_launch(void* const* d_in, const int* in_sizes, int n_in,
                              void* d_out, int out_size, void* d_ws, size_t ws_size,
                              hipStream_t stream) {
  float* ws = (float*)d_ws;
  int* flag = (int*)(ws + WS_FLAG);

  P36 ptrs;
  for (int i = 0; i < 36; i++) ptrs.p[i] = d_in[i];

  float* sF     = ws + OFF_S;
  float* WpostR = ws + WS_WPOSTR;
  float* WresR  = ws + WS_WRESR;
  float* hpost  = ws + WS_HPOST;
  float* rowsum = ws + WS_ROWSUM;
  float* rotb   = ws + WS_ROTB;
  float* Wcat   = ws + WS_WCAT;
  float* proj   = ws + WS_PROJ;
  float* Oext   = ws + WS_PROJ;               // overlay (proj dead after assemble)
  float* x3     = ws + WS_PROJ;               // overlay (Oext dead after feat_k)
  float* Qext   = ws + WS_QEXT;
  float* featb  = ws + WS_QEXT;               // overlay (Q/K dead after attn), spans into KEXT
  float* sipa   = ws + WS_QEXT;               // overlay (feat dead after ipa GEMM)
  float* Kext   = ws + WS_KEXT;
  float* Vext   = ws + WS_VEXT;
  float* x1s1   = ws + WS_VEXT;               // overlay (V dead after attn): x1 then s1 in-place
  float* t1b    = ws + WS_VEXT + 1572864;
  float* t2b    = ws + WS_VEXT + 3145728;

  detect_k<<<1, 64, 0, stream>>>((const unsigned int*)d_in[5], flag);
  cvtall_k<<<(IN_END + 255) / 256, 256, 0, stream>>>(ptrs, ws, flag);
  concat_k<<<2880, 256, 0, stream>>>(ws + OFF_WQ, ws + OFF_WK, ws + OFF_WV,
                                     ws + OFF_WQP, ws + OFF_WKP, ws + OFF_WVP, Wcat);
  wreduce_k<<<24, 256, 0, stream>>>(ws + OFF_WPOST, ws + OFF_WRES, WpostR, WresR);
  mhc_k<<<BL, 64, 0, stream>>>(sF, ws + OFF_QUAT, ws + OFF_BPOST, ws + OFF_BRES, ws + OFF_ALPHA,
                               WpostR, WresR, hpost, rowsum, rotb);
  gemm_k<<<dim3(30, 64), 256, 0, stream>>>(sF, Wcat, nullptr, proj, BL, NPROJ, CSD, 0);
  assemble_k<<<128, 256, 0, stream>>>(proj, rotb, ws + OFF_TRANS, ws + OFF_Z1, ws + OFF_Z2,
                                      ws + OFF_WZQ, ws + OFF_WZK, ws + OFF_HEADW, Qext, Kext, Vext);
  attn_k<<<dim3(32, 32), 256, 0, stream>>>(Qext, Kext, Vext, ws + OFF_MASK, Oext);
  feat_k<<<128, 256, 0, stream>>>(Oext, rotb, ws + OFF_TRANS, featb);
  gemm_k<<<dim3(6, 64), 256, 0, stream>>>(featb, ws + OFF_WO, ws + OFF_BO, x1s1, BL, CSD, FEATD, 0);
  ln_k<<<BL, 64, 0, stream>>>(x1s1, sF, ws + OFF_LN1G, ws + OFF_LN1B, x1s1);                   // s1
  gemm_k<<<dim3(6, 64), 256, 0, stream>>>(x1s1, ws + OFF_WT1, ws + OFF_BT1, t1b, BL, CSD, CSD, 1);
  gemm_k<<<dim3(6, 64), 256, 0, stream>>>(t1b, ws + OFF_WT2, ws + OFF_BT2, t2b, BL, CSD, CSD, 1);
  gemm_k<<<dim3(6, 64), 256, 0, stream>>>(t2b, ws + OFF_WT3, ws + OFF_BT3, x3, BL, CSD, CSD, 0);
  ln_k<<<BL, 64, 0, stream>>>(x3, x1s1, ws + OFF_LNTG, ws + OFF_LNTB, sipa);                   // s_ipa
  final_k<<<BL, 64, 0, stream>>>(sF, sipa, rotb, ws + OFF_TRANS, hpost, rowsum,
                                 ws + OFF_WBB, ws + OFF_BBB, flag, d_out);
}

// Round 3
// 634.087 us; speedup vs baseline: 1.7914x; 1.7914x over previous
//
#include <hip/hip_runtime.h>
#include <hip/hip_bf16.h>

typedef __hip_bfloat16 bf16;
typedef float f4v __attribute__((ext_vector_type(4)));
typedef short s8v __attribute__((ext_vector_type(8)));

#define CSD    384
#define LL     1024
#define NH     8
#define BL     4096        // B*L
#define NPROJ  1920
#define QDP    96          // 80 real ext-Q/K dims, padded to 96
#define VDP    160         // 152 real ext-V dims, padded to 160
#define FEATD  1280

// ---- fp32 input mirror layout (float offsets inside d_ws) ----
#define OFF_S      0
#define OFF_Z1     1572864
#define OFF_Z2     2621440
#define OFF_QUAT   4718592
#define OFF_TRANS  4734976
#define OFF_MASK   4747264
#define OFF_BPOST  4751360
#define OFF_BRES   4751376
#define OFF_WPOST  4751392
#define OFF_WRES   4757536
#define OFF_ALPHA  4782112
#define OFF_WQ     4782128
#define OFF_WK     4978736
#define OFF_WV     5175344
#define OFF_WQP    5371952
#define OFF_WKP    5408816
#define OFF_WVP    5445680
#define OFF_WZQ    5519408
#define OFF_WZK    5520432
#define OFF_HEADW  5521456
#define OFF_WO     5521472
#define OFF_BO     6012992
#define OFF_LN1G   6013376
#define OFF_LN1B   6013760
#define OFF_WT1    6014144
#define OFF_BT1    6161600
#define OFF_WT2    6161984
#define OFF_BT2    6309440
#define OFF_WT3    6309824
#define OFF_BT3    6457280
#define OFF_LNTG   6457664
#define OFF_LNTB   6458048
#define OFF_WBB    6458432
#define OFF_BBB    6460736
#define IN_END     6460752

// ---- scratch layout after the mirror (float offsets) ----
#define WS_FLAG    6460752
#define WS_WPOSTR  6460768      // 1,536
#define WS_WRESR   6462304      // 6,144
#define WS_HPOST   6468448      // 16,384
#define WS_ROWSUM  6484832      // 16,384
#define WS_ROTB    6501216      // 36,864
#define WS_WCAT    6538080      // 737,280 fp32 concat weights [384,1920]
#define WS_PROJ    7275360      // 7,864,320 floats ; overlays: Oext, x1/s1, x3
#define WS_QB      15139680     // bf16 Q [32][1024][96]  (1,572,864 float slots)
#define WS_KB      16712544     // bf16 K [32][1024][96]  (1,572,864 float slots)
#define WS_VT      18285408     // bf16 V^T [32][160][1024] (2,621,440 float slots)
// end: 20,906,848 floats = 83.6 MB

#define OUT_ROT 6291456
#define OUT_TR  6328320

#define NSEG 34

struct P36 { const void* p[36]; };

__device__ __forceinline__ float b2f(bf16 x) { return __bfloat162float(x); }

// float -> bf16 bits (round-to-nearest-even)
__device__ __forceinline__ short f2bs(float x) {
  unsigned u = __float_as_uint(x);
  u += 0x7FFFu + ((u >> 16) & 1u);
  return (short)(u >> 16);
}

__device__ __forceinline__ float wredf(float v) {
#pragma unroll
  for (int o = 1; o < 64; o <<= 1) v += __shfl_xor(v, o, 64);
  return v;
}

// ---------- dtype detect: mask is all-ones; bf16 pair = 0x3F803F80, fp32 = 0x3F800000 ----------
__global__ void detect_k(const unsigned int* __restrict__ mask_raw, int* __restrict__ flag) {
  if (threadIdx.x == 0 && blockIdx.x == 0) flag[0] = (mask_raw[0] == 0x3F803F80u) ? 1 : 0;
}

// ---------- convert ALL inputs into contiguous fp32 mirror ----------
__global__ __launch_bounds__(256) void cvtall_k(P36 ptrs, float* __restrict__ dst, const int* __restrict__ flagp) {
  const int i = blockIdx.x * 256 + threadIdx.x;
  if (i >= IN_END) return;
  const int flag = flagp[0];
  const int seg_src_t[NSEG] = {0,1,2,3,4,5,7,8,10,11,12,13,14,15,16,17,18,19,20,21,22,23,24,25,26,27,28,29,30,31,32,33,34,35};
  const int seg_dst_t[NSEG] = {OFF_S,OFF_Z1,OFF_Z2,OFF_QUAT,OFF_TRANS,OFF_MASK,OFF_BPOST,OFF_BRES,OFF_WPOST,OFF_WRES,
                               OFF_ALPHA,OFF_WQ,OFF_WK,OFF_WV,OFF_WQP,OFF_WKP,OFF_WVP,OFF_WZQ,OFF_WZK,OFF_HEADW,
                               OFF_WO,OFF_BO,OFF_LN1G,OFF_LN1B,OFF_WT1,OFF_BT1,OFF_WT2,OFF_BT2,OFF_WT3,OFF_BT3,
                               OFF_LNTG,OFF_LNTB,OFF_WBB,OFF_BBB};
  const int seg_cnt_t[NSEG] = {1572864,1048576,2097152,16384,12288,4096,4,16,6144,24576,
                               1,196608,196608,196608,36864,36864,73728,1024,1024,8,
                               491520,384,384,384,147456,384,147456,384,147456,384,
                               384,384,2304,6};
  int off = i, cnt = seg_cnt_t[0];
  const void* sp = ptrs.p[0];
#pragma unroll
  for (int k = 1; k < NSEG; k++) {
    if (i >= seg_dst_t[k]) { off = i - seg_dst_t[k]; cnt = seg_cnt_t[k]; sp = ptrs.p[seg_src_t[k]]; }
  }
  float v = 0.f;
  if (off < cnt) {
    v = flag ? b2f(((const bf16*)sp)[off]) : ((const float*)sp)[off];
  }
  dst[i] = v;
}

// ---------- concat projection weights into fp32 [384,1920] ----------
__global__ __launch_bounds__(256) void concat_k(const float* __restrict__ Wq, const float* __restrict__ Wk,
                                                const float* __restrict__ Wv, const float* __restrict__ Wqp,
                                                const float* __restrict__ Wkp, const float* __restrict__ Wvp,
                                                float* __restrict__ Wcat) {
  int i = blockIdx.x * 256 + threadIdx.x;
  if (i >= CSD * NPROJ) return;
  int k = i / NPROJ, c = i % NPROJ;
  float v;
  if (c < 512)       v = Wq[k * 512 + c];
  else if (c < 1024) v = Wk[k * 512 + c - 512];
  else if (c < 1536) v = Wv[k * 512 + c - 1024];
  else if (c < 1632) v = Wqp[k * 96 + c - 1536];
  else if (c < 1728) v = Wkp[k * 96 + c - 1632];
  else               v = Wvp[k * 192 + c - 1728];
  Wcat[i] = v;
}

// ---------- reduce W_post [1536,4]->[384,4], W_res [1536,16]->[384,16] ----------
__global__ __launch_bounds__(256) void wreduce_k(const float* __restrict__ Wpost, const float* __restrict__ Wres,
                                                 float* __restrict__ WpostR, float* __restrict__ WresR) {
  int i = blockIdx.x * 256 + threadIdx.x;
  if (i < CSD * 4) {
    int c = i >> 2, n = i & 3;
    float s = 0.f;
#pragma unroll
    for (int blk = 0; blk < 4; blk++) s += Wpost[(blk * CSD + c) * 4 + n];
    WpostR[i] = s;
  }
  if (i < CSD * 16) {
    int c = i >> 4, n = i & 15;
    float s = 0.f;
#pragma unroll
    for (int blk = 0; blk < 4; blk++) s += Wres[(blk * CSD + c) * 16 + n];
    WresR[i] = s;
  }
}

// ---------- per-residue: H_post, sinkhorn row-sums, quat->rot ----------
__global__ __launch_bounds__(64) void mhc_k(const float* __restrict__ sF, const float* __restrict__ quat,
                                            const float* __restrict__ bpost, const float* __restrict__ bres,
                                            const float* __restrict__ alpha_p, const float* __restrict__ WpostR,
                                            const float* __restrict__ WresR, float* __restrict__ hpost,
                                            float* __restrict__ rowsum, float* __restrict__ rotb) {
  const int bl = blockIdx.x, t = threadIdx.x;
  const float* sr = sF + (size_t)bl * CSD;
  float ssq = 0.f, dp[4] = {0.f, 0.f, 0.f, 0.f}, dr[16];
#pragma unroll
  for (int n = 0; n < 16; n++) dr[n] = 0.f;
#pragma unroll
  for (int e = 0; e < 6; e++) {
    const int c = t + e * 64;
    const float sv = sr[c];
    ssq = fmaf(sv, sv, ssq);
#pragma unroll
    for (int n = 0; n < 4; n++) dp[n] = fmaf(sv, WpostR[c * 4 + n], dp[n]);
#pragma unroll
    for (int n = 0; n < 16; n++) dr[n] = fmaf(sv, WresR[c * 16 + n], dr[n]);
  }
  ssq = wredf(ssq);
#pragma unroll
  for (int n = 0; n < 4; n++) dp[n] = wredf(dp[n]);
#pragma unroll
  for (int n = 0; n < 16; n++) dr[n] = wredf(dr[n]);
  const float alpha = alpha_p[0];
  const float invn = rsqrtf(ssq * (1.f / 384.f) + 1e-6f);
  if (t == 0) {
#pragma unroll
    for (int n = 0; n < 4; n++) {
      const float x = bpost[n] + alpha * invn * dp[n];
      hpost[bl * 4 + n] = 2.f / (1.f + __expf(-x));
    }
    float M[16];
    float mx = -1e30f;
#pragma unroll
    for (int k = 0; k < 16; k++) { M[k] = bres[k] + alpha * invn * dr[k]; mx = fmaxf(mx, M[k]); }
#pragma unroll
    for (int k = 0; k < 16; k++) M[k] = __expf(M[k] - mx);
    for (int it = 0; it < 20; it++) {
#pragma unroll
      for (int r = 0; r < 4; r++) {
        const float s4 = M[r * 4] + M[r * 4 + 1] + M[r * 4 + 2] + M[r * 4 + 3];
        const float iv = 1.f / (s4 + 1e-8f);
        M[r * 4] *= iv; M[r * 4 + 1] *= iv; M[r * 4 + 2] *= iv; M[r * 4 + 3] *= iv;
      }
#pragma unroll
      for (int c2 = 0; c2 < 4; c2++) {
        const float s4 = M[c2] + M[4 + c2] + M[8 + c2] + M[12 + c2];
        const float iv = 1.f / (s4 + 1e-8f);
        M[c2] *= iv; M[4 + c2] *= iv; M[8 + c2] *= iv; M[12 + c2] *= iv;
      }
    }
#pragma unroll
    for (int r = 0; r < 4; r++)
      rowsum[bl * 4 + r] = M[r * 4] + M[r * 4 + 1] + M[r * 4 + 2] + M[r * 4 + 3];
  }
  if (t == 1) {
    float w = quat[bl * 4 + 0], x = quat[bl * 4 + 1];
    float y = quat[bl * 4 + 2], z = quat[bl * 4 + 3];
    const float iq = rsqrtf(w * w + x * x + y * y + z * z + 1e-8f);
    w *= iq; x *= iq; y *= iq; z *= iq;
    float* R = rotb + (size_t)bl * 9;
    R[0] = 1.f - 2.f * (y * y + z * z); R[1] = 2.f * (x * y - w * z); R[2] = 2.f * (x * z + w * y);
    R[3] = 2.f * (x * y + w * z); R[4] = 1.f - 2.f * (x * x + z * z); R[5] = 2.f * (y * z - w * x);
    R[6] = 2.f * (x * z - w * y); R[7] = 2.f * (y * z + w * x); R[8] = 1.f - 2.f * (x * x + y * y);
  }
}

// ---------- generic fp32 tiled GEMM: C[M,N] = A[M,K] @ B[K,N] (+bias)(+relu) ----------
__global__ __launch_bounds__(256) void gemm_k(const float* __restrict__ A, const float* __restrict__ Bw,
                                              const float* __restrict__ bias, float* __restrict__ C,
                                              int M, int N, int K, int relu) {
  __shared__ __align__(16) float As[16][68];
  __shared__ __align__(16) float Bs[16][68];
  const int tid = threadIdx.x;
  const int tx = tid & 15, ty = tid >> 4;
  const int bm = blockIdx.y, bn = blockIdx.x;
  const float* Ab = A + (size_t)bm * 64 * K;
  const float* Bb = Bw + bn * 64;
  float acc[4][4];
#pragma unroll
  for (int i = 0; i < 4; i++)
#pragma unroll
    for (int j = 0; j < 4; j++) acc[i][j] = 0.f;
  for (int k0 = 0; k0 < K; k0 += 16) {
#pragma unroll
    for (int e = 0; e < 4; e++) {
      const int idx = tid + e * 256;
      const int m = idx >> 4, kk = idx & 15;
      As[kk][m] = Ab[(size_t)m * K + k0 + kk];
    }
#pragma unroll
    for (int e = 0; e < 4; e++) {
      const int idx = tid + e * 256;
      const int kk = idx >> 6, n = idx & 63;
      Bs[kk][n] = Bb[(size_t)(k0 + kk) * N + n];
    }
    __syncthreads();
#pragma unroll
    for (int kk = 0; kk < 16; kk++) {
      const float4 a4 = *(const float4*)&As[kk][ty * 4];
      const float4 b4 = *(const float4*)&Bs[kk][tx * 4];
      const float av[4] = {a4.x, a4.y, a4.z, a4.w};
      const float bv[4] = {b4.x, b4.y, b4.z, b4.w};
#pragma unroll
      for (int i = 0; i < 4; i++)
#pragma unroll
        for (int j = 0; j < 4; j++) acc[i][j] = fmaf(av[i], bv[j], acc[i][j]);
    }
    __syncthreads();
  }
#pragma unroll
  for (int i = 0; i < 4; i++) {
    const int m = bm * 64 + ty * 4 + i;
#pragma unroll
    for (int j = 0; j < 4; j++) {
      const int n = bn * 64 + tx * 4 + j;
      float v = acc[i][j];
      if (bias != nullptr) v += bias[n];
      if (relu) v = fmaxf(v, 0.f);
      C[(size_t)m * N + n] = v;
    }
  }
}

// ---------- assemble extended Q/K (bf16, [bh][L][96]) and V^T (bf16, [bh][160][L]) ----------
__global__ __launch_bounds__(256) void assemble_k(const float* __restrict__ proj, const float* __restrict__ rotb,
                                                  const float* __restrict__ trans, const float* __restrict__ z1,
                                                  const float* __restrict__ z2, const float* __restrict__ Wzq,
                                                  const float* __restrict__ Wzk, const float* __restrict__ headw,
                                                  short* __restrict__ Qb, short* __restrict__ Kb,
                                                  short* __restrict__ Vtb) {
  const int idx = blockIdx.x * 256 + threadIdx.x;  // < 32768
  const int h = idx & 7, bl = idx >> 3;
  const float* pr = proj + (size_t)bl * NPROJ;
  const float* R = rotb + (size_t)bl * 9;
  const float txx = trans[bl * 3 + 0], tyy = trans[bl * 3 + 1], tzz = trans[bl * 3 + 2];
  float gamma;
  { const float w = headw[h]; gamma = (w > 20.f) ? w : log1pf(__expf(w)); }
  const float wL = 0.57735026918962576f;  // sqrt(1/3)
  const float wC = 0.23570226039551584f;  // sqrt(2/(9*4))
  const float ch = wL * wC * 0.5f * gamma;
  const float qscale = wL * 0.125f;       // wL / sqrt(64)

  float zq0 = 0.f, zq1 = 0.f, zk0 = 0.f, zk1 = 0.f;
  const float* z1r = z1 + (size_t)bl * 256;
  for (int zz = 0; zz < 128; zz++) {
    const float wq = Wzq[zz * 8 + h], wk = Wzk[zz * 8 + h];
    const float a0 = z1r[zz], a1 = z1r[128 + zz];
    zq0 = fmaf(a0, wq, zq0); zq1 = fmaf(a1, wq, zq1);
    zk0 = fmaf(a0, wk, zk0); zk1 = fmaf(a1, wk, zk1);
  }
  const int b = bl >> 10, l = bl & 1023;
  const size_t row = (size_t)(b * NH + h) * LL + l;
  short* Q = Qb + row * QDP;
  short* Kx = Kb + row * QDP;
  for (int c = 0; c < 64; c++) { Q[c] = f2bs(pr[h * 64 + c] * qscale); Kx[c] = f2bs(pr[512 + h * 64 + c]); }
  Q[64] = f2bs(wL * zq0); Q[65] = f2bs(wL * zq1);
  Kx[64] = f2bs(zk0); Kx[65] = f2bs(zk1);
  float qn = 0.f, kn = 0.f;
#pragma unroll
  for (int p = 0; p < 4; p++) {
    const float* pl = pr + 1536 + h * 12 + p * 3;
    float gx = R[0] * pl[0] + R[1] * pl[1] + R[2] * pl[2] + txx;
    float gy = R[3] * pl[0] + R[4] * pl[1] + R[5] * pl[2] + tyy;
    float gz = R[6] * pl[0] + R[7] * pl[1] + R[8] * pl[2] + tzz;
    qn += gx * gx + gy * gy + gz * gz;
    Q[66 + p * 3 + 0] = f2bs(2.f * ch * gx); Q[66 + p * 3 + 1] = f2bs(2.f * ch * gy); Q[66 + p * 3 + 2] = f2bs(2.f * ch * gz);
    const float* pk = pr + 1632 + h * 12 + p * 3;
    gx = R[0] * pk[0] + R[1] * pk[1] + R[2] * pk[2] + txx;
    gy = R[3] * pk[0] + R[4] * pk[1] + R[5] * pk[2] + tyy;
    gz = R[6] * pk[0] + R[7] * pk[1] + R[8] * pk[2] + tzz;
    kn += gx * gx + gy * gy + gz * gz;
    Kx[66 + p * 3 + 0] = f2bs(gx); Kx[66 + p * 3 + 1] = f2bs(gy); Kx[66 + p * 3 + 2] = f2bs(gz);
  }
  Q[78] = f2bs(-ch * qn); Q[79] = f2bs(1.f);
  Kx[78] = f2bs(1.f);     Kx[79] = f2bs(-ch * kn);
  for (int c = 80; c < QDP; c++) { Q[c] = 0; Kx[c] = 0; }
  // V transposed: Vtb[bh][c][l]
  const size_t vbase = (size_t)(b * NH + h) * VDP * LL + l;
  for (int c = 0; c < 64; c++) Vtb[vbase + (size_t)c * LL] = f2bs(pr[1024 + h * 64 + c]);
#pragma unroll
  for (int p = 0; p < 8; p++) {
    const float* pv = pr + 1728 + h * 24 + p * 3;
    const float gx = R[0] * pv[0] + R[1] * pv[1] + R[2] * pv[2] + txx;
    const float gy = R[3] * pv[0] + R[4] * pv[1] + R[5] * pv[2] + tyy;
    const float gz = R[6] * pv[0] + R[7] * pv[1] + R[8] * pv[2] + tzz;
    Vtb[vbase + (size_t)(64 + p * 3 + 0) * LL] = f2bs(gx);
    Vtb[vbase + (size_t)(64 + p * 3 + 1) * LL] = f2bs(gy);
    Vtb[vbase + (size_t)(64 + p * 3 + 2) * LL] = f2bs(gz);
  }
  const float* z2r = z2 + ((size_t)bl * NH + h) * 64;
  for (int c = 0; c < 64; c++) Vtb[vbase + (size_t)(88 + c) * LL] = f2bs(z2r[c]);
  for (int c = 152; c < VDP; c++) Vtb[vbase + (size_t)c * LL] = 0;
}

// ---------- MFMA flash attention: 4 waves x 16 q-rows per block, j-tiles of 32 ----------
__global__ __launch_bounds__(256) void attn_k(const short* __restrict__ Qb, const short* __restrict__ Kb,
                                              const short* __restrict__ Vtb, const float* __restrict__ maskF,
                                              float* __restrict__ Oext) {
  __shared__ __align__(16) short Ks[32 * 104];   // K tile row-major, padded stride 104
  __shared__ __align__(16) short Vs[160 * 40];   // V^T tile, padded stride 40
  __shared__ __align__(16) short Ps[4 * 16 * 40];// per-wave P staging, stride 40
  __shared__ float Msl[32];
  const int tid = threadIdx.x;
  const int wid = tid >> 6;
  const int lane = tid & 63;
  const int c15 = lane & 15;
  const int q = lane >> 4;
  const int bh = blockIdx.y;
  const int b = bh >> 3, h = bh & 7;
  const int i0 = blockIdx.x * 64 + wid * 16;

  // persistent Q A-fragments: lane holds row i0+c15, k = kc*32 + q*8 + [0..7]
  s8v Qa[3];
  const short* Qrow = Qb + ((size_t)bh * LL + i0 + c15) * QDP;
#pragma unroll
  for (int kc = 0; kc < 3; kc++) Qa[kc] = *(const s8v*)(Qrow + kc * 32 + q * 8);

  f4v Of[10];
#pragma unroll
  for (int vt = 0; vt < 10; vt++) Of[vt] = (f4v){0.f, 0.f, 0.f, 0.f};
  float mold[4] = {-1e30f, -1e30f, -1e30f, -1e30f};
  float lsum[4] = {0.f, 0.f, 0.f, 0.f};

  const short* Kbase = Kb + (size_t)bh * LL * QDP;
  const short* Vbase = Vtb + (size_t)bh * VDP * LL;
  short* Pl = Ps + wid * 640;

  for (int jt = 0; jt < 32; jt++) {
    const int j0 = jt * 32;
    __syncthreads();
    // stage K tile (32 rows x 96) -> Ks
    for (int u = tid; u < 384; u += 256) {
      const int r = u / 12, cc = u % 12;
      *(int4*)&Ks[r * 104 + cc * 8] = *(const int4*)(Kbase + (size_t)(j0 + r) * QDP + cc * 8);
    }
    // stage V^T tile (160 cols x 32 j) -> Vs
    for (int u = tid; u < 640; u += 256) {
      const int cc = u >> 2, part = u & 3;
      *(int4*)&Vs[cc * 40 + part * 8] = *(const int4*)(Vbase + (size_t)cc * LL + j0 + part * 8);
    }
    if (tid < 32) Msl[tid] = maskF[b * LL + j0 + tid];
    __syncthreads();

    // QK^T: D[i 16][j 32] as two 16-col subtiles
    f4v Sf0 = (f4v){0.f, 0.f, 0.f, 0.f}, Sf1 = (f4v){0.f, 0.f, 0.f, 0.f};
#pragma unroll
    for (int kc = 0; kc < 3; kc++) {
      const s8v K0 = *(const s8v*)&Ks[c15 * 104 + kc * 32 + q * 8];
      const s8v K1 = *(const s8v*)&Ks[(16 + c15) * 104 + kc * 32 + q * 8];
      Sf0 = __builtin_amdgcn_mfma_f32_16x16x32_bf16(Qa[kc], K0, Sf0, 0, 0, 0);
      Sf1 = __builtin_amdgcn_mfma_f32_16x16x32_bf16(Qa[kc], K1, Sf1, 0, 0, 0);
    }
    const float mv0 = Msl[c15], mv1 = Msl[16 + c15];
    float lg0[4], lg1[4], tm[4], al[4], p0[4], p1[4];
#pragma unroll
    for (int r = 0; r < 4; r++) {
      lg0[r] = (mv0 > 0.f) ? Sf0[r] : -1e9f;
      lg1[r] = (mv1 > 0.f) ? Sf1[r] : -1e9f;
      tm[r] = fmaxf(lg0[r], lg1[r]);
    }
#pragma unroll
    for (int r = 0; r < 4; r++) {
      tm[r] = fmaxf(tm[r], __shfl_xor(tm[r], 1, 64));
      tm[r] = fmaxf(tm[r], __shfl_xor(tm[r], 2, 64));
      tm[r] = fmaxf(tm[r], __shfl_xor(tm[r], 4, 64));
      tm[r] = fmaxf(tm[r], __shfl_xor(tm[r], 8, 64));
    }
#pragma unroll
    for (int r = 0; r < 4; r++) {
      const float mn = fmaxf(mold[r], tm[r]);
      al[r] = __expf(mold[r] - mn);
      mold[r] = mn;
      p0[r] = __expf(lg0[r] - mn);
      p1[r] = __expf(lg1[r] - mn);
      lsum[r] = lsum[r] * al[r] + p0[r] + p1[r];
    }
#pragma unroll
    for (int vt = 0; vt < 10; vt++) {
#pragma unroll
      for (int r = 0; r < 4; r++) Of[vt][r] *= al[r];
    }
    // P: C-layout (row=q*4+r, col=subtile*16+c15) -> LDS -> A-layout read
#pragma unroll
    for (int r = 0; r < 4; r++) {
      Pl[(q * 4 + r) * 40 + c15] = f2bs(p0[r]);
      Pl[(q * 4 + r) * 40 + 16 + c15] = f2bs(p1[r]);
    }
    __syncthreads();
    const s8v Pa = *(const s8v*)&Pl[c15 * 40 + q * 8];
#pragma unroll
    for (int vt = 0; vt < 10; vt++) {
      const s8v Vf = *(const s8v*)&Vs[(vt * 16 + c15) * 40 + q * 8];
      Of[vt] = __builtin_amdgcn_mfma_f32_16x16x32_bf16(Pa, Vf, Of[vt], 0, 0, 0);
    }
  }
  // reduce lsum across the 16 lanes of each quad, normalize, store
#pragma unroll
  for (int r = 0; r < 4; r++) {
    lsum[r] += __shfl_xor(lsum[r], 1, 64);
    lsum[r] += __shfl_xor(lsum[r], 2, 64);
    lsum[r] += __shfl_xor(lsum[r], 4, 64);
    lsum[r] += __shfl_xor(lsum[r], 8, 64);
  }
#pragma unroll
  for (int r = 0; r < 4; r++) {
    const float inv = 1.f / lsum[r];
    const int i = i0 + q * 4 + r;
    float* Or = Oext + ((size_t)(b * LL + i) * NH + h) * VDP;
#pragma unroll
    for (int vt = 0; vt < 10; vt++) Or[vt * 16 + c15] = Of[vt][r] * inv;
  }
}

// ---------- feat assembly: local-frame transform + norms (thread per (b,l,h)) ----------
__global__ __launch_bounds__(256) void feat_k(const float* __restrict__ Oext, const float* __restrict__ rotb,
                                              const float* __restrict__ trans, float* __restrict__ feat) {
  const int idx = blockIdx.x * 256 + threadIdx.x;
  const int h = idx & 7, bl = idx >> 3;
  const float* O = Oext + (size_t)(bl * 8 + h) * VDP;
  float* f = feat + (size_t)bl * FEATD;
  for (int c = 0; c < 64; c++) f[h * 64 + c] = O[c];
  const float* R = rotb + (size_t)bl * 9;
  const float txx = trans[bl * 3 + 0], tyy = trans[bl * 3 + 1], tzz = trans[bl * 3 + 2];
#pragma unroll
  for (int p = 0; p < 8; p++) {
    const float dx = O[64 + p * 3 + 0] - txx;
    const float dy = O[64 + p * 3 + 1] - tyy;
    const float dz = O[64 + p * 3 + 2] - tzz;
    const float lx = R[0] * dx + R[3] * dy + R[6] * dz;   // R^T * diff
    const float ly = R[1] * dx + R[4] * dy + R[7] * dz;
    const float lz = R[2] * dx + R[5] * dy + R[8] * dz;
    f[512 + h * 24 + p * 3 + 0] = lx;
    f[512 + h * 24 + p * 3 + 1] = ly;
    f[512 + h * 24 + p * 3 + 2] = lz;
    f[704 + h * 8 + p] = sqrtf(lx * lx + ly * ly + lz * lz + 1e-8f);
  }
  for (int c = 0; c < 64; c++) f[768 + h * 64 + c] = O[88 + c];
}

// ---------- LayerNorm(x + resid) (one wave per row) ----------
__global__ __launch_bounds__(64) void ln_k(const float* __restrict__ x, const float* __restrict__ resid,
                                           const float* __restrict__ g, const float* __restrict__ bta,
                                           float* __restrict__ out) {
  const int row = blockIdx.x, t = threadIdx.x;
  const float* xr = x + (size_t)row * CSD;
  const float* rr = resid + (size_t)row * CSD;
  float v[6];
  float s = 0.f;
#pragma unroll
  for (int e = 0; e < 6; e++) {
    const int c = t + e * 64;
    v[e] = xr[c] + rr[c];
    s += v[e];
  }
  s = wredf(s);
  const float mu = s * (1.f / 384.f);
  float var = 0.f;
#pragma unroll
  for (int e = 0; e < 6; e++) { const float d = v[e] - mu; var = fmaf(d, d, var); }
  var = wredf(var) * (1.f / 384.f);
  const float inv = rsqrtf(var + 1e-5f);
#pragma unroll
  for (int e = 0; e < 6; e++) {
    const int c = t + e * 64;
    out[(size_t)row * CSD + c] = (v[e] - mu) * inv * g[c] + bta[c];
  }
}

// ---------- final: backbone update + mHC combine; writes output per dtype flag ----------
__global__ __launch_bounds__(64) void final_k(const float* __restrict__ sF, const float* __restrict__ sipa,
                                              const float* __restrict__ rotb, const float* __restrict__ trans,
                                              const float* __restrict__ hpost, const float* __restrict__ rowsum,
                                              const float* __restrict__ Wbb, const float* __restrict__ bbb,
                                              const int* __restrict__ flagp, void* __restrict__ outv) {
  const int bl = blockIdx.x, t = threadIdx.x;
  const int flag = flagp[0];
  bf16* outb = (bf16*)outv;
  float* outf = (float*)outv;
  const float* si = sipa + (size_t)bl * CSD;
  float d6[6] = {0.f, 0.f, 0.f, 0.f, 0.f, 0.f};
#pragma unroll
  for (int e = 0; e < 6; e++) {
    const int c = t + e * 64;
    const float v = si[c];
#pragma unroll
    for (int u = 0; u < 6; u++) d6[u] = fmaf(v, Wbb[c * 6 + u], d6[u]);
  }
#pragma unroll
  for (int u = 0; u < 6; u++) d6[u] = wredf(d6[u]);
  float upd[6];
#pragma unroll
  for (int u = 0; u < 6; u++) upd[u] = d6[u] + bbb[u];
  const float* R = rotb + (size_t)bl * 9;
  if (t == 0) {
    float w = 1.f, x = upd[0], y = upd[1], z = upd[2];
    const float iq = rsqrtf(w * w + x * x + y * y + z * z + 1e-8f);
    w *= iq; x *= iq; y *= iq; z *= iq;
    const float Ru[9] = {1.f - 2.f * (y * y + z * z), 2.f * (x * y - w * z), 2.f * (x * z + w * y),
                         2.f * (x * y + w * z), 1.f - 2.f * (x * x + z * z), 2.f * (y * z - w * x),
                         2.f * (x * z - w * y), 2.f * (y * z + w * x), 1.f - 2.f * (x * x + y * y)};
#pragma unroll
    for (int i = 0; i < 3; i++)
#pragma unroll
      for (int j = 0; j < 3; j++) {
        const float rv = R[i * 3 + 0] * Ru[0 + j] + R[i * 3 + 1] * Ru[3 + j] + R[i * 3 + 2] * Ru[6 + j];
        const size_t o = OUT_ROT + (size_t)bl * 9 + i * 3 + j;
        if (flag) outb[o] = __float2bfloat16(rv); else outf[o] = rv;
      }
#pragma unroll
    for (int i = 0; i < 3; i++) {
      const float tv = R[i * 3 + 0] * upd[3] + R[i * 3 + 1] * upd[4] + R[i * 3 + 2] * upd[5] + trans[bl * 3 + i];
      const size_t o = OUT_TR + (size_t)bl * 3 + i;
      if (flag) outb[o] = __float2bfloat16(tv); else outf[o] = tv;
    }
  }
  const float hp0 = hpost[bl * 4 + 0], hp1 = hpost[bl * 4 + 1], hp2 = hpost[bl * 4 + 2], hp3 = hpost[bl * 4 + 3];
  const float rs0 = rowsum[bl * 4 + 0], rs1 = rowsum[bl * 4 + 1], rs2 = rowsum[bl * 4 + 2], rs3 = rowsum[bl * 4 + 3];
  const float* sr = sF + (size_t)bl * CSD;
#pragma unroll
  for (int e = 0; e < 6; e++) {
    const int c = t + e * 64;
    const float sv = sr[c], sp = si[c];
    const size_t base = (size_t)bl * 4 * CSD + c;
    const float o0 = rs0 * sv + hp0 * sp;
    const float o1 = rs1 * sv + hp1 * sp;
    const float o2 = rs2 * sv + hp2 * sp;
    const float o3 = rs3 * sv + hp3 * sp;
    if (flag) {
      outb[base + 0 * CSD] = __float2bfloat16(o0);
      outb[base + 1 * CSD] = __float2bfloat16(o1);
      outb[base + 2 * CSD] = __float2bfloat16(o2);
      outb[base + 3 * CSD] = __float2bfloat16(o3);
    } else {
      outf[base + 0 * CSD] = o0;
      outf[base + 1 * CSD] = o1;
      outf[base + 2 * CSD] = o2;
      outf[base + 3 * CSD] = o3;
    }
  }
}

extern "C" void kernel_launch(void* const* d_in, const int* in_sizes, int n_in,
                              void* d_out, int out_size, void* d_ws, size_t ws_size,
                              hipStream_t stream) {
  float* ws = (float*)d_ws;
  int* flag = (int*)(ws + WS_FLAG);

  P36 ptrs;
  for (int i = 0; i < 36; i++) ptrs.p[i] = d_in[i];

  float* sF     = ws + OFF_S;
  float* WpostR = ws + WS_WPOSTR;
  float* WresR  = ws + WS_WRESR;
  float* hpost  = ws + WS_HPOST;
  float* rowsum = ws + WS_ROWSUM;
  float* rotb   = ws + WS_ROTB;
  float* Wcat   = ws + WS_WCAT;
  float* proj   = ws + WS_PROJ;
  short* Qb     = (short*)(ws + WS_QB);
  short* Kb     = (short*)(ws + WS_KB);
  short* Vtb    = (short*)(ws + WS_VT);
  float* Oext   = ws + WS_PROJ;               // overlay (proj dead after assemble)
  float* featb  = ws + WS_QB;                 // overlay (Q/K/V^T dead after attn)
  float* x1s1   = ws + WS_PROJ;               // overlay (Oext dead after feat_k)
  float* t1b    = ws + WS_QB;                 // overlay (feat dead after Wo gemm)
  float* t2b    = ws + WS_KB;                 // overlay (disjoint from t1)
  float* x3     = ws + WS_PROJ + 1572864;     // s1 at WS_PROJ stays alive
  float* sipa   = ws + WS_KB;                 // overlay (t2 dead after x3 gemm)

  detect_k<<<1, 64, 0, stream>>>((const unsigned int*)d_in[5], flag);
  cvtall_k<<<(IN_END + 255) / 256, 256, 0, stream>>>(ptrs, ws, flag);
  concat_k<<<2880, 256, 0, stream>>>(ws + OFF_WQ, ws + OFF_WK, ws + OFF_WV,
                                     ws + OFF_WQP, ws + OFF_WKP, ws + OFF_WVP, Wcat);
  wreduce_k<<<24, 256, 0, stream>>>(ws + OFF_WPOST, ws + OFF_WRES, WpostR, WresR);
  mhc_k<<<BL, 64, 0, stream>>>(sF, ws + OFF_QUAT, ws + OFF_BPOST, ws + OFF_BRES, ws + OFF_ALPHA,
                               WpostR, WresR, hpost, rowsum, rotb);
  gemm_k<<<dim3(30, 64), 256, 0, stream>>>(sF, Wcat, nullptr, proj, BL, NPROJ, CSD, 0);
  assemble_k<<<128, 256, 0, stream>>>(proj, rotb, ws + OFF_TRANS, ws + OFF_Z1, ws + OFF_Z2,
                                      ws + OFF_WZQ, ws + OFF_WZK, ws + OFF_HEADW, Qb, Kb, Vtb);
  attn_k<<<dim3(16, 32), 256, 0, stream>>>(Qb, Kb, Vtb, ws + OFF_MASK, Oext);
  feat_k<<<128, 256, 0, stream>>>(Oext, rotb, ws + OFF_TRANS, featb);
  gemm_k<<<dim3(6, 64), 256, 0, stream>>>(featb, ws + OFF_WO, ws + OFF_BO, x1s1, BL, CSD, FEATD, 0);
  ln_k<<<BL, 64, 0, stream>>>(x1s1, sF, ws + OFF_LN1G, ws + OFF_LN1B, x1s1);                   // s1
  gemm_k<<<dim3(6, 64), 256, 0, stream>>>(x1s1, ws + OFF_WT1, ws + OFF_BT1, t1b, BL, CSD, CSD, 1);
  gemm_k<<<dim3(6, 64), 256, 0, stream>>>(t1b, ws + OFF_WT2, ws + OFF_BT2, t2b, BL, CSD, CSD, 1);
  gemm_k<<<dim3(6, 64), 256, 0, stream>>>(t2b, ws + OFF_WT3, ws + OFF_BT3, x3, BL, CSD, CSD, 0);
  ln_k<<<BL, 64, 0, stream>>>(x3, x1s1, ws + OFF_LNTG, ws + OFF_LNTB, sipa);                   // s_ipa
  final_k<<<BL, 64, 0, stream>>>(sF, sipa, rotb, ws + OFF_TRANS, hpost, rowsum,
                                 ws + OFF_WBB, ws + OFF_BBB, flag, d_out);
}

// Round 4
// 543.690 us; speedup vs baseline: 2.0893x; 1.1663x over previous
//
#include <hip/hip_runtime.h>
#include <hip/hip_bf16.h>

typedef __hip_bfloat16 bf16;
typedef float f4v __attribute__((ext_vector_type(4)));
typedef short s8v __attribute__((ext_vector_type(8)));

#define CSD    384
#define LL     1024
#define NH     8
#define BL     4096        // B*L
#define NPROJ  1920
#define QDP    96          // 80 real ext-Q/K dims, padded to 96
#define VDP    160         // 152 real ext-V dims, padded to 160
#define FEATD  1280

// ---- fp32 input mirror layout (float offsets inside d_ws) ----
#define OFF_S      0
#define OFF_Z1     1572864
#define OFF_Z2     2621440
#define OFF_QUAT   4718592
#define OFF_TRANS  4734976
#define OFF_MASK   4747264
#define OFF_BPOST  4751360
#define OFF_BRES   4751376
#define OFF_WPOST  4751392
#define OFF_WRES   4757536
#define OFF_ALPHA  4782112
#define OFF_WQ     4782128
#define OFF_WK     4978736
#define OFF_WV     5175344
#define OFF_WQP    5371952
#define OFF_WKP    5408816
#define OFF_WVP    5445680
#define OFF_WZQ    5519408
#define OFF_WZK    5520432
#define OFF_HEADW  5521456
#define OFF_WO     5521472
#define OFF_BO     6012992
#define OFF_LN1G   6013376
#define OFF_LN1B   6013760
#define OFF_WT1    6014144
#define OFF_BT1    6161600
#define OFF_WT2    6161984
#define OFF_BT2    6309440
#define OFF_WT3    6309824
#define OFF_BT3    6457280
#define OFF_LNTG   6457664
#define OFF_LNTB   6458048
#define OFF_WBB    6458432
#define OFF_BBB    6460736
#define IN_END     6460752

// ---- scratch layout after the mirror (float offsets) ----
#define WS_FLAG    6460752
#define WS_WPOSTR  6460768      // 1,536
#define WS_WRESR   6462304      // 6,144
#define WS_HPOST   6468448      // 16,384
#define WS_ROWSUM  6484832      // 16,384
#define WS_ROTB    6501216      // 36,864
#define WS_WCATT   6538080      // bf16 Wcat^T [1920][384]  (368,640 f32 slots)
#define WS_PROJ    7275360      // 7,864,320 floats ; overlays: Oext, x1/s1, x3
#define WS_QB      15139680     // bf16 Q [32][1024][96]  (1,572,864 f32 slots)
#define WS_KB      16712544     // bf16 K [32][1024][96]  (1,572,864 f32 slots)
#define WS_VT      18285408     // bf16 V^T [32][160][1024] (2,621,440 f32 slots)
#define WS_WOT     20906848     // bf16 Wo^T [384][1280] (245,760 f32 slots)
#define WS_WT1T    21152608     // bf16 Wt1^T [384][384] (73,728)
#define WS_WT2T    21226336
#define WS_WT3T    21300064
// end: 21,373,792 floats = 85.5 MB

#define OUT_ROT 6291456
#define OUT_TR  6328320

#define NSEG 34

struct P36 { const void* p[36]; };

__device__ __forceinline__ float b2f(bf16 x) { return __bfloat162float(x); }

// float -> bf16 bits (round-to-nearest-even)
__device__ __forceinline__ short f2bs(float x) {
  unsigned u = __float_as_uint(x);
  u += 0x7FFFu + ((u >> 16) & 1u);
  return (short)(u >> 16);
}

__device__ __forceinline__ float wredf(float v) {
#pragma unroll
  for (int o = 1; o < 64; o <<= 1) v += __shfl_xor(v, o, 64);
  return v;
}

// ---------- dtype detect: mask is all-ones; bf16 pair = 0x3F803F80, fp32 = 0x3F800000 ----------
__global__ void detect_k(const unsigned int* __restrict__ mask_raw, int* __restrict__ flag) {
  if (threadIdx.x == 0 && blockIdx.x == 0) flag[0] = (mask_raw[0] == 0x3F803F80u) ? 1 : 0;
}

// ---------- convert ALL inputs into contiguous fp32 mirror ----------
__global__ __launch_bounds__(256) void cvtall_k(P36 ptrs, float* __restrict__ dst, const int* __restrict__ flagp) {
  const int i = blockIdx.x * 256 + threadIdx.x;
  if (i >= IN_END) return;
  const int flag = flagp[0];
  const int seg_src_t[NSEG] = {0,1,2,3,4,5,7,8,10,11,12,13,14,15,16,17,18,19,20,21,22,23,24,25,26,27,28,29,30,31,32,33,34,35};
  const int seg_dst_t[NSEG] = {OFF_S,OFF_Z1,OFF_Z2,OFF_QUAT,OFF_TRANS,OFF_MASK,OFF_BPOST,OFF_BRES,OFF_WPOST,OFF_WRES,
                               OFF_ALPHA,OFF_WQ,OFF_WK,OFF_WV,OFF_WQP,OFF_WKP,OFF_WVP,OFF_WZQ,OFF_WZK,OFF_HEADW,
                               OFF_WO,OFF_BO,OFF_LN1G,OFF_LN1B,OFF_WT1,OFF_BT1,OFF_WT2,OFF_BT2,OFF_WT3,OFF_BT3,
                               OFF_LNTG,OFF_LNTB,OFF_WBB,OFF_BBB};
  const int seg_cnt_t[NSEG] = {1572864,1048576,2097152,16384,12288,4096,4,16,6144,24576,
                               1,196608,196608,196608,36864,36864,73728,1024,1024,8,
                               491520,384,384,384,147456,384,147456,384,147456,384,
                               384,384,2304,6};
  int off = i, cnt = seg_cnt_t[0];
  const void* sp = ptrs.p[0];
#pragma unroll
  for (int k = 1; k < NSEG; k++) {
    if (i >= seg_dst_t[k]) { off = i - seg_dst_t[k]; cnt = seg_cnt_t[k]; sp = ptrs.p[seg_src_t[k]]; }
  }
  float v = 0.f;
  if (off < cnt) {
    v = flag ? b2f(((const bf16*)sp)[off]) : ((const float*)sp)[off];
  }
  dst[i] = v;
}

// ---------- build Wcat^T bf16 [1920][384] from fp32 mirror weights ----------
__global__ __launch_bounds__(256) void wcatT_k(const float* __restrict__ Wq, const float* __restrict__ Wk,
                                               const float* __restrict__ Wv, const float* __restrict__ Wqp,
                                               const float* __restrict__ Wkp, const float* __restrict__ Wvp,
                                               short* __restrict__ WcatT) {
  int i = blockIdx.x * 256 + threadIdx.x;    // i = k*1920 + n (coalesced reads)
  if (i >= CSD * NPROJ) return;
  int k = i / NPROJ, c = i % NPROJ;
  float v;
  if (c < 512)       v = Wq[k * 512 + c];
  else if (c < 1024) v = Wk[k * 512 + c - 512];
  else if (c < 1536) v = Wv[k * 512 + c - 1024];
  else if (c < 1632) v = Wqp[k * 96 + c - 1536];
  else if (c < 1728) v = Wkp[k * 96 + c - 1632];
  else               v = Wvp[k * 192 + c - 1728];
  WcatT[c * CSD + k] = f2bs(v);
}

// ---------- generic transpose fp32 [K][N] -> bf16 [N][K] ----------
__global__ __launch_bounds__(256) void wT_k(const float* __restrict__ W, short* __restrict__ Wt, int K, int N) {
  int i = blockIdx.x * 256 + threadIdx.x;    // i = k*N + n (coalesced reads)
  if (i >= K * N) return;
  int k = i / N, n = i % N;
  Wt[(size_t)n * K + k] = f2bs(W[i]);
}

// ---------- reduce W_post [1536,4]->[384,4], W_res [1536,16]->[384,16] ----------
__global__ __launch_bounds__(256) void wreduce_k(const float* __restrict__ Wpost, const float* __restrict__ Wres,
                                                 float* __restrict__ WpostR, float* __restrict__ WresR) {
  int i = blockIdx.x * 256 + threadIdx.x;
  if (i < CSD * 4) {
    int c = i >> 2, n = i & 3;
    float s = 0.f;
#pragma unroll
    for (int blk = 0; blk < 4; blk++) s += Wpost[(blk * CSD + c) * 4 + n];
    WpostR[i] = s;
  }
  if (i < CSD * 16) {
    int c = i >> 4, n = i & 15;
    float s = 0.f;
#pragma unroll
    for (int blk = 0; blk < 4; blk++) s += Wres[(blk * CSD + c) * 16 + n];
    WresR[i] = s;
  }
}

// ---------- per-residue: H_post, sinkhorn row-sums, quat->rot ----------
__global__ __launch_bounds__(64) void mhc_k(const float* __restrict__ sF, const float* __restrict__ quat,
                                            const float* __restrict__ bpost, const float* __restrict__ bres,
                                            const float* __restrict__ alpha_p, const float* __restrict__ WpostR,
                                            const float* __restrict__ WresR, float* __restrict__ hpost,
                                            float* __restrict__ rowsum, float* __restrict__ rotb) {
  const int bl = blockIdx.x, t = threadIdx.x;
  const float* sr = sF + (size_t)bl * CSD;
  float ssq = 0.f, dp[4] = {0.f, 0.f, 0.f, 0.f}, dr[16];
#pragma unroll
  for (int n = 0; n < 16; n++) dr[n] = 0.f;
#pragma unroll
  for (int e = 0; e < 6; e++) {
    const int c = t + e * 64;
    const float sv = sr[c];
    ssq = fmaf(sv, sv, ssq);
#pragma unroll
    for (int n = 0; n < 4; n++) dp[n] = fmaf(sv, WpostR[c * 4 + n], dp[n]);
#pragma unroll
    for (int n = 0; n < 16; n++) dr[n] = fmaf(sv, WresR[c * 16 + n], dr[n]);
  }
  ssq = wredf(ssq);
#pragma unroll
  for (int n = 0; n < 4; n++) dp[n] = wredf(dp[n]);
#pragma unroll
  for (int n = 0; n < 16; n++) dr[n] = wredf(dr[n]);
  const float alpha = alpha_p[0];
  const float invn = rsqrtf(ssq * (1.f / 384.f) + 1e-6f);
  if (t == 0) {
#pragma unroll
    for (int n = 0; n < 4; n++) {
      const float x = bpost[n] + alpha * invn * dp[n];
      hpost[bl * 4 + n] = 2.f / (1.f + __expf(-x));
    }
    float M[16];
    float mx = -1e30f;
#pragma unroll
    for (int k = 0; k < 16; k++) { M[k] = bres[k] + alpha * invn * dr[k]; mx = fmaxf(mx, M[k]); }
#pragma unroll
    for (int k = 0; k < 16; k++) M[k] = __expf(M[k] - mx);
    for (int it = 0; it < 20; it++) {
#pragma unroll
      for (int r = 0; r < 4; r++) {
        const float s4 = M[r * 4] + M[r * 4 + 1] + M[r * 4 + 2] + M[r * 4 + 3];
        const float iv = 1.f / (s4 + 1e-8f);
        M[r * 4] *= iv; M[r * 4 + 1] *= iv; M[r * 4 + 2] *= iv; M[r * 4 + 3] *= iv;
      }
#pragma unroll
      for (int c2 = 0; c2 < 4; c2++) {
        const float s4 = M[c2] + M[4 + c2] + M[8 + c2] + M[12 + c2];
        const float iv = 1.f / (s4 + 1e-8f);
        M[c2] *= iv; M[4 + c2] *= iv; M[8 + c2] *= iv; M[12 + c2] *= iv;
      }
    }
#pragma unroll
    for (int r = 0; r < 4; r++)
      rowsum[bl * 4 + r] = M[r * 4] + M[r * 4 + 1] + M[r * 4 + 2] + M[r * 4 + 3];
  }
  if (t == 1) {
    float w = quat[bl * 4 + 0], x = quat[bl * 4 + 1];
    float y = quat[bl * 4 + 2], z = quat[bl * 4 + 3];
    const float iq = rsqrtf(w * w + x * x + y * y + z * z + 1e-8f);
    w *= iq; x *= iq; y *= iq; z *= iq;
    float* R = rotb + (size_t)bl * 9;
    R[0] = 1.f - 2.f * (y * y + z * z); R[1] = 2.f * (x * y - w * z); R[2] = 2.f * (x * z + w * y);
    R[3] = 2.f * (x * y + w * z); R[4] = 1.f - 2.f * (x * x + z * z); R[5] = 2.f * (y * z - w * x);
    R[6] = 2.f * (x * z - w * y); R[7] = 2.f * (y * z + w * x); R[8] = 1.f - 2.f * (x * x + y * y);
  }
}

// ---------- MFMA bf16 GEMM: C[M,N](fp32) = A[M,K](fp32) @ Bt[N,K](bf16)^T (+bias)(+relu)
// 128x128 tile, 4 waves in 2x2, each wave 64x64 via 4x4 grid of 16x16x32 MFMA
__global__ __launch_bounds__(256) void gemm_mfma_k(const float* __restrict__ A, const short* __restrict__ Bt,
                                                   const float* __restrict__ bias, float* __restrict__ C,
                                                   int M, int N, int K, int relu) {
  __shared__ __align__(16) short As[128 * 40];
  __shared__ __align__(16) short Bs[128 * 40];
  const int tid = threadIdx.x;
  const int wid = tid >> 6, lane = tid & 63;
  const int c15 = lane & 15, q = lane >> 4;
  const int bm = blockIdx.y, bn = blockIdx.x;
  const int m_wave = (wid & 1) * 64, n_wave = (wid >> 1) * 64;
  const float* Ab = A + (size_t)(bm * 128) * K;
  const short* Bb = Bt + (size_t)(bn * 128) * K;

  f4v acc[4][4];
#pragma unroll
  for (int mi = 0; mi < 4; mi++)
#pragma unroll
    for (int ni = 0; ni < 4; ni++) acc[mi][ni] = (f4v){0.f, 0.f, 0.f, 0.f};

  for (int k0 = 0; k0 < K; k0 += 32) {
    __syncthreads();
    // stage A: 128 rows x 32 k, fp32 -> bf16
#pragma unroll
    for (int e = 0; e < 4; e++) {
      const int slot = tid + e * 256;           // 1024 float4 slots
      const int m = slot >> 3, k4 = (slot & 7) * 4;
      const float4 a = *(const float4*)(Ab + (size_t)m * K + k0 + k4);
      short pk[4] = {f2bs(a.x), f2bs(a.y), f2bs(a.z), f2bs(a.w)};
      *(int2*)&As[m * 40 + k4] = *(const int2*)pk;
    }
    // stage B^T: 128 n-rows x 32 k bf16
#pragma unroll
    for (int e = 0; e < 2; e++) {
      const int slot = tid + e * 256;           // 512 slots of 8 bf16
      const int n = slot >> 2, k8 = (slot & 3) * 8;
      *(int4*)&Bs[n * 40 + k8] = *(const int4*)(Bb + (size_t)n * K + k0 + k8);
    }
    __syncthreads();
    s8v Af[4], Bf[4];
#pragma unroll
    for (int mi = 0; mi < 4; mi++) Af[mi] = *(const s8v*)&As[(m_wave + mi * 16 + c15) * 40 + q * 8];
#pragma unroll
    for (int ni = 0; ni < 4; ni++) Bf[ni] = *(const s8v*)&Bs[(n_wave + ni * 16 + c15) * 40 + q * 8];
#pragma unroll
    for (int mi = 0; mi < 4; mi++)
#pragma unroll
      for (int ni = 0; ni < 4; ni++)
        acc[mi][ni] = __builtin_amdgcn_mfma_f32_16x16x32_bf16(Af[mi], Bf[ni], acc[mi][ni], 0, 0, 0);
  }
  // epilogue: C row = bm*128 + m_wave + mi*16 + q*4 + r ; col = bn*128 + n_wave + ni*16 + c15
#pragma unroll
  for (int mi = 0; mi < 4; mi++) {
#pragma unroll
    for (int r = 0; r < 4; r++) {
      const int row = bm * 128 + m_wave + mi * 16 + q * 4 + r;
      float* Cr = C + (size_t)row * N + bn * 128 + n_wave;
#pragma unroll
      for (int ni = 0; ni < 4; ni++) {
        const int col = bn * 128 + n_wave + ni * 16 + c15;
        float v = acc[mi][ni][r];
        if (bias != nullptr) v += bias[col];
        if (relu) v = fmaxf(v, 0.f);
        Cr[ni * 16 + c15] = v;
      }
    }
  }
}

// ---------- assemble extended Q/K (bf16, [bh][L][96]) and V^T (bf16, [bh][160][L]) ----------
__global__ __launch_bounds__(256) void assemble_k(const float* __restrict__ proj, const float* __restrict__ rotb,
                                                  const float* __restrict__ trans, const float* __restrict__ z1,
                                                  const float* __restrict__ z2, const float* __restrict__ Wzq,
                                                  const float* __restrict__ Wzk, const float* __restrict__ headw,
                                                  short* __restrict__ Qb, short* __restrict__ Kb,
                                                  short* __restrict__ Vtb) {
  const int idx = blockIdx.x * 256 + threadIdx.x;  // < 32768
  const int h = idx & 7, bl = idx >> 3;
  const float* pr = proj + (size_t)bl * NPROJ;
  const float* R = rotb + (size_t)bl * 9;
  const float txx = trans[bl * 3 + 0], tyy = trans[bl * 3 + 1], tzz = trans[bl * 3 + 2];
  float gamma;
  { const float w = headw[h]; gamma = (w > 20.f) ? w : log1pf(__expf(w)); }
  const float wL = 0.57735026918962576f;  // sqrt(1/3)
  const float wC = 0.23570226039551584f;  // sqrt(2/(9*4))
  const float ch = wL * wC * 0.5f * gamma;
  const float qscale = wL * 0.125f;       // wL / sqrt(64)

  float zq0 = 0.f, zq1 = 0.f, zk0 = 0.f, zk1 = 0.f;
  const float* z1r = z1 + (size_t)bl * 256;
  for (int zz = 0; zz < 128; zz++) {
    const float wq = Wzq[zz * 8 + h], wk = Wzk[zz * 8 + h];
    const float a0 = z1r[zz], a1 = z1r[128 + zz];
    zq0 = fmaf(a0, wq, zq0); zq1 = fmaf(a1, wq, zq1);
    zk0 = fmaf(a0, wk, zk0); zk1 = fmaf(a1, wk, zk1);
  }
  const int b = bl >> 10, l = bl & 1023;
  const size_t row = (size_t)(b * NH + h) * LL + l;
  short* Q = Qb + row * QDP;
  short* Kx = Kb + row * QDP;
  for (int c = 0; c < 64; c++) { Q[c] = f2bs(pr[h * 64 + c] * qscale); Kx[c] = f2bs(pr[512 + h * 64 + c]); }
  Q[64] = f2bs(wL * zq0); Q[65] = f2bs(wL * zq1);
  Kx[64] = f2bs(zk0); Kx[65] = f2bs(zk1);
  float qn = 0.f, kn = 0.f;
#pragma unroll
  for (int p = 0; p < 4; p++) {
    const float* pl = pr + 1536 + h * 12 + p * 3;
    float gx = R[0] * pl[0] + R[1] * pl[1] + R[2] * pl[2] + txx;
    float gy = R[3] * pl[0] + R[4] * pl[1] + R[5] * pl[2] + tyy;
    float gz = R[6] * pl[0] + R[7] * pl[1] + R[8] * pl[2] + tzz;
    qn += gx * gx + gy * gy + gz * gz;
    Q[66 + p * 3 + 0] = f2bs(2.f * ch * gx); Q[66 + p * 3 + 1] = f2bs(2.f * ch * gy); Q[66 + p * 3 + 2] = f2bs(2.f * ch * gz);
    const float* pk = pr + 1632 + h * 12 + p * 3;
    gx = R[0] * pk[0] + R[1] * pk[1] + R[2] * pk[2] + txx;
    gy = R[3] * pk[0] + R[4] * pk[1] + R[5] * pk[2] + tyy;
    gz = R[6] * pk[0] + R[7] * pk[1] + R[8] * pk[2] + tzz;
    kn += gx * gx + gy * gy + gz * gz;
    Kx[66 + p * 3 + 0] = f2bs(gx); Kx[66 + p * 3 + 1] = f2bs(gy); Kx[66 + p * 3 + 2] = f2bs(gz);
  }
  Q[78] = f2bs(-ch * qn); Q[79] = f2bs(1.f);
  Kx[78] = f2bs(1.f);     Kx[79] = f2bs(-ch * kn);
  for (int c = 80; c < QDP; c++) { Q[c] = 0; Kx[c] = 0; }
  // V transposed: Vtb[bh][c][l]
  const size_t vbase = (size_t)(b * NH + h) * VDP * LL + l;
  for (int c = 0; c < 64; c++) Vtb[vbase + (size_t)c * LL] = f2bs(pr[1024 + h * 64 + c]);
#pragma unroll
  for (int p = 0; p < 8; p++) {
    const float* pv = pr + 1728 + h * 24 + p * 3;
    const float gx = R[0] * pv[0] + R[1] * pv[1] + R[2] * pv[2] + txx;
    const float gy = R[3] * pv[0] + R[4] * pv[1] + R[5] * pv[2] + tyy;
    const float gz = R[6] * pv[0] + R[7] * pv[1] + R[8] * pv[2] + tzz;
    Vtb[vbase + (size_t)(64 + p * 3 + 0) * LL] = f2bs(gx);
    Vtb[vbase + (size_t)(64 + p * 3 + 1) * LL] = f2bs(gy);
    Vtb[vbase + (size_t)(64 + p * 3 + 2) * LL] = f2bs(gz);
  }
  const float* z2r = z2 + ((size_t)bl * NH + h) * 64;
  for (int c = 0; c < 64; c++) Vtb[vbase + (size_t)(88 + c) * LL] = f2bs(z2r[c]);
  for (int c = 152; c < VDP; c++) Vtb[vbase + (size_t)c * LL] = 0;
}

// ---------- MFMA flash attention: 4 waves x 16 q-rows per block, j-tiles of 32 ----------
__global__ __launch_bounds__(256) void attn_k(const short* __restrict__ Qb, const short* __restrict__ Kb,
                                              const short* __restrict__ Vtb, const float* __restrict__ maskF,
                                              float* __restrict__ Oext) {
  __shared__ __align__(16) short Ks[32 * 104];   // K tile row-major, padded stride 104
  __shared__ __align__(16) short Vs[160 * 40];   // V^T tile, padded stride 40
  __shared__ __align__(16) short Ps[4 * 16 * 40];// per-wave P staging, stride 40
  __shared__ float Msl[32];
  const int tid = threadIdx.x;
  const int wid = tid >> 6;
  const int lane = tid & 63;
  const int c15 = lane & 15;
  const int q = lane >> 4;
  const int bh = blockIdx.y;
  const int b = bh >> 3, h = bh & 7;
  const int i0 = blockIdx.x * 64 + wid * 16;

  s8v Qa[3];
  const short* Qrow = Qb + ((size_t)bh * LL + i0 + c15) * QDP;
#pragma unroll
  for (int kc = 0; kc < 3; kc++) Qa[kc] = *(const s8v*)(Qrow + kc * 32 + q * 8);

  f4v Of[10];
#pragma unroll
  for (int vt = 0; vt < 10; vt++) Of[vt] = (f4v){0.f, 0.f, 0.f, 0.f};
  float mold[4] = {-1e30f, -1e30f, -1e30f, -1e30f};
  float lsum[4] = {0.f, 0.f, 0.f, 0.f};

  const short* Kbase = Kb + (size_t)bh * LL * QDP;
  const short* Vbase = Vtb + (size_t)bh * VDP * LL;
  short* Pl = Ps + wid * 640;

  for (int jt = 0; jt < 32; jt++) {
    const int j0 = jt * 32;
    __syncthreads();
    for (int u = tid; u < 384; u += 256) {
      const int r = u / 12, cc = u % 12;
      *(int4*)&Ks[r * 104 + cc * 8] = *(const int4*)(Kbase + (size_t)(j0 + r) * QDP + cc * 8);
    }
    for (int u = tid; u < 640; u += 256) {
      const int cc = u >> 2, part = u & 3;
      *(int4*)&Vs[cc * 40 + part * 8] = *(const int4*)(Vbase + (size_t)cc * LL + j0 + part * 8);
    }
    if (tid < 32) Msl[tid] = maskF[b * LL + j0 + tid];
    __syncthreads();

    f4v Sf0 = (f4v){0.f, 0.f, 0.f, 0.f}, Sf1 = (f4v){0.f, 0.f, 0.f, 0.f};
#pragma unroll
    for (int kc = 0; kc < 3; kc++) {
      const s8v K0 = *(const s8v*)&Ks[c15 * 104 + kc * 32 + q * 8];
      const s8v K1 = *(const s8v*)&Ks[(16 + c15) * 104 + kc * 32 + q * 8];
      Sf0 = __builtin_amdgcn_mfma_f32_16x16x32_bf16(Qa[kc], K0, Sf0, 0, 0, 0);
      Sf1 = __builtin_amdgcn_mfma_f32_16x16x32_bf16(Qa[kc], K1, Sf1, 0, 0, 0);
    }
    const float mv0 = Msl[c15], mv1 = Msl[16 + c15];
    float lg0[4], lg1[4], tm[4], al[4], p0[4], p1[4];
#pragma unroll
    for (int r = 0; r < 4; r++) {
      lg0[r] = (mv0 > 0.f) ? Sf0[r] : -1e9f;
      lg1[r] = (mv1 > 0.f) ? Sf1[r] : -1e9f;
      tm[r] = fmaxf(lg0[r], lg1[r]);
    }
#pragma unroll
    for (int r = 0; r < 4; r++) {
      tm[r] = fmaxf(tm[r], __shfl_xor(tm[r], 1, 64));
      tm[r] = fmaxf(tm[r], __shfl_xor(tm[r], 2, 64));
      tm[r] = fmaxf(tm[r], __shfl_xor(tm[r], 4, 64));
      tm[r] = fmaxf(tm[r], __shfl_xor(tm[r], 8, 64));
    }
#pragma unroll
    for (int r = 0; r < 4; r++) {
      const float mn = fmaxf(mold[r], tm[r]);
      al[r] = __expf(mold[r] - mn);
      mold[r] = mn;
      p0[r] = __expf(lg0[r] - mn);
      p1[r] = __expf(lg1[r] - mn);
      lsum[r] = lsum[r] * al[r] + p0[r] + p1[r];
    }
#pragma unroll
    for (int vt = 0; vt < 10; vt++) {
#pragma unroll
      for (int r = 0; r < 4; r++) Of[vt][r] *= al[r];
    }
#pragma unroll
    for (int r = 0; r < 4; r++) {
      Pl[(q * 4 + r) * 40 + c15] = f2bs(p0[r]);
      Pl[(q * 4 + r) * 40 + 16 + c15] = f2bs(p1[r]);
    }
    __syncthreads();
    const s8v Pa = *(const s8v*)&Pl[c15 * 40 + q * 8];
#pragma unroll
    for (int vt = 0; vt < 10; vt++) {
      const s8v Vf = *(const s8v*)&Vs[(vt * 16 + c15) * 40 + q * 8];
      Of[vt] = __builtin_amdgcn_mfma_f32_16x16x32_bf16(Pa, Vf, Of[vt], 0, 0, 0);
    }
  }
#pragma unroll
  for (int r = 0; r < 4; r++) {
    lsum[r] += __shfl_xor(lsum[r], 1, 64);
    lsum[r] += __shfl_xor(lsum[r], 2, 64);
    lsum[r] += __shfl_xor(lsum[r], 4, 64);
    lsum[r] += __shfl_xor(lsum[r], 8, 64);
  }
#pragma unroll
  for (int r = 0; r < 4; r++) {
    const float inv = 1.f / lsum[r];
    const int i = i0 + q * 4 + r;
    float* Or = Oext + ((size_t)(b * LL + i) * NH + h) * VDP;
#pragma unroll
    for (int vt = 0; vt < 10; vt++) Or[vt * 16 + c15] = Of[vt][r] * inv;
  }
}

// ---------- feat assembly: local-frame transform + norms (thread per (b,l,h)) ----------
__global__ __launch_bounds__(256) void feat_k(const float* __restrict__ Oext, const float* __restrict__ rotb,
                                              const float* __restrict__ trans, float* __restrict__ feat) {
  const int idx = blockIdx.x * 256 + threadIdx.x;
  const int h = idx & 7, bl = idx >> 3;
  const float* O = Oext + (size_t)(bl * 8 + h) * VDP;
  float* f = feat + (size_t)bl * FEATD;
  for (int c = 0; c < 64; c++) f[h * 64 + c] = O[c];
  const float* R = rotb + (size_t)bl * 9;
  const float txx = trans[bl * 3 + 0], tyy = trans[bl * 3 + 1], tzz = trans[bl * 3 + 2];
#pragma unroll
  for (int p = 0; p < 8; p++) {
    const float dx = O[64 + p * 3 + 0] - txx;
    const float dy = O[64 + p * 3 + 1] - tyy;
    const float dz = O[64 + p * 3 + 2] - tzz;
    const float lx = R[0] * dx + R[3] * dy + R[6] * dz;   // R^T * diff
    const float ly = R[1] * dx + R[4] * dy + R[7] * dz;
    const float lz = R[2] * dx + R[5] * dy + R[8] * dz;
    f[512 + h * 24 + p * 3 + 0] = lx;
    f[512 + h * 24 + p * 3 + 1] = ly;
    f[512 + h * 24 + p * 3 + 2] = lz;
    f[704 + h * 8 + p] = sqrtf(lx * lx + ly * ly + lz * lz + 1e-8f);
  }
  for (int c = 0; c < 64; c++) f[768 + h * 64 + c] = O[88 + c];
}

// ---------- LayerNorm(x + resid) (one wave per row) ----------
__global__ __launch_bounds__(64) void ln_k(const float* __restrict__ x, const float* __restrict__ resid,
                                           const float* __restrict__ g, const float* __restrict__ bta,
                                           float* __restrict__ out) {
  const int row = blockIdx.x, t = threadIdx.x;
  const float* xr = x + (size_t)row * CSD;
  const float* rr = resid + (size_t)row * CSD;
  float v[6];
  float s = 0.f;
#pragma unroll
  for (int e = 0; e < 6; e++) {
    const int c = t + e * 64;
    v[e] = xr[c] + rr[c];
    s += v[e];
  }
  s = wredf(s);
  const float mu = s * (1.f / 384.f);
  float var = 0.f;
#pragma unroll
  for (int e = 0; e < 6; e++) { const float d = v[e] - mu; var = fmaf(d, d, var); }
  var = wredf(var) * (1.f / 384.f);
  const float inv = rsqrtf(var + 1e-5f);
#pragma unroll
  for (int e = 0; e < 6; e++) {
    const int c = t + e * 64;
    out[(size_t)row * CSD + c] = (v[e] - mu) * inv * g[c] + bta[c];
  }
}

// ---------- final: backbone update + mHC combine; writes output per dtype flag ----------
__global__ __launch_bounds__(64) void final_k(const float* __restrict__ sF, const float* __restrict__ sipa,
                                              const float* __restrict__ rotb, const float* __restrict__ trans,
                                              const float* __restrict__ hpost, const float* __restrict__ rowsum,
                                              const float* __restrict__ Wbb, const float* __restrict__ bbb,
                                              const int* __restrict__ flagp, void* __restrict__ outv) {
  const int bl = blockIdx.x, t = threadIdx.x;
  const int flag = flagp[0];
  bf16* outb = (bf16*)outv;
  float* outf = (float*)outv;
  const float* si = sipa + (size_t)bl * CSD;
  float d6[6] = {0.f, 0.f, 0.f, 0.f, 0.f, 0.f};
#pragma unroll
  for (int e = 0; e < 6; e++) {
    const int c = t + e * 64;
    const float v = si[c];
#pragma unroll
    for (int u = 0; u < 6; u++) d6[u] = fmaf(v, Wbb[c * 6 + u], d6[u]);
  }
#pragma unroll
  for (int u = 0; u < 6; u++) d6[u] = wredf(d6[u]);
  float upd[6];
#pragma unroll
  for (int u = 0; u < 6; u++) upd[u] = d6[u] + bbb[u];
  const float* R = rotb + (size_t)bl * 9;
  if (t == 0) {
    float w = 1.f, x = upd[0], y = upd[1], z = upd[2];
    const float iq = rsqrtf(w * w + x * x + y * y + z * z + 1e-8f);
    w *= iq; x *= iq; y *= iq; z *= iq;
    const float Ru[9] = {1.f - 2.f * (y * y + z * z), 2.f * (x * y - w * z), 2.f * (x * z + w * y),
                         2.f * (x * y + w * z), 1.f - 2.f * (x * x + z * z), 2.f * (y * z - w * x),
                         2.f * (x * z - w * y), 2.f * (y * z + w * x), 1.f - 2.f * (x * x + y * y)};
#pragma unroll
    for (int i = 0; i < 3; i++)
#pragma unroll
      for (int j = 0; j < 3; j++) {
        const float rv = R[i * 3 + 0] * Ru[0 + j] + R[i * 3 + 1] * Ru[3 + j] + R[i * 3 + 2] * Ru[6 + j];
        const size_t o = OUT_ROT + (size_t)bl * 9 + i * 3 + j;
        if (flag) outb[o] = __float2bfloat16(rv); else outf[o] = rv;
      }
#pragma unroll
    for (int i = 0; i < 3; i++) {
      const float tv = R[i * 3 + 0] * upd[3] + R[i * 3 + 1] * upd[4] + R[i * 3 + 2] * upd[5] + trans[bl * 3 + i];
      const size_t o = OUT_TR + (size_t)bl * 3 + i;
      if (flag) outb[o] = __float2bfloat16(tv); else outf[o] = tv;
    }
  }
  const float hp0 = hpost[bl * 4 + 0], hp1 = hpost[bl * 4 + 1], hp2 = hpost[bl * 4 + 2], hp3 = hpost[bl * 4 + 3];
  const float rs0 = rowsum[bl * 4 + 0], rs1 = rowsum[bl * 4 + 1], rs2 = rowsum[bl * 4 + 2], rs3 = rowsum[bl * 4 + 3];
  const float* sr = sF + (size_t)bl * CSD;
#pragma unroll
  for (int e = 0; e < 6; e++) {
    const int c = t + e * 64;
    const float sv = sr[c], sp = si[c];
    const size_t base = (size_t)bl * 4 * CSD + c;
    const float o0 = rs0 * sv + hp0 * sp;
    const float o1 = rs1 * sv + hp1 * sp;
    const float o2 = rs2 * sv + hp2 * sp;
    const float o3 = rs3 * sv + hp3 * sp;
    if (flag) {
      outb[base + 0 * CSD] = __float2bfloat16(o0);
      outb[base + 1 * CSD] = __float2bfloat16(o1);
      outb[base + 2 * CSD] = __float2bfloat16(o2);
      outb[base + 3 * CSD] = __float2bfloat16(o3);
    } else {
      outf[base + 0 * CSD] = o0;
      outf[base + 1 * CSD] = o1;
      outf[base + 2 * CSD] = o2;
      outf[base + 3 * CSD] = o3;
    }
  }
}

extern "C" void kernel_launch(void* const* d_in, const int* in_sizes, int n_in,
                              void* d_out, int out_size, void* d_ws, size_t ws_size,
                              hipStream_t stream) {
  float* ws = (float*)d_ws;
  int* flag = (int*)(ws + WS_FLAG);

  P36 ptrs;
  for (int i = 0; i < 36; i++) ptrs.p[i] = d_in[i];

  float* sF     = ws + OFF_S;
  float* WpostR = ws + WS_WPOSTR;
  float* WresR  = ws + WS_WRESR;
  float* hpost  = ws + WS_HPOST;
  float* rowsum = ws + WS_ROWSUM;
  float* rotb   = ws + WS_ROTB;
  short* WcatT  = (short*)(ws + WS_WCATT);
  short* WoT    = (short*)(ws + WS_WOT);
  short* Wt1T   = (short*)(ws + WS_WT1T);
  short* Wt2T   = (short*)(ws + WS_WT2T);
  short* Wt3T   = (short*)(ws + WS_WT3T);
  float* proj   = ws + WS_PROJ;
  short* Qb     = (short*)(ws + WS_QB);
  short* Kb     = (short*)(ws + WS_KB);
  short* Vtb    = (short*)(ws + WS_VT);
  float* Oext   = ws + WS_PROJ;               // overlay (proj dead after assemble)
  float* featb  = ws + WS_QB;                 // overlay (Q/K/V^T dead after attn)
  float* x1s1   = ws + WS_PROJ;               // overlay (Oext dead after feat_k)
  float* t1b    = ws + WS_QB;                 // overlay (feat dead after Wo gemm)
  float* t2b    = ws + WS_KB;                 // overlay (disjoint from t1)
  float* x3     = ws + WS_PROJ + 1572864;     // s1 at WS_PROJ stays alive
  float* sipa   = ws + WS_KB;                 // overlay (t2 dead after x3 gemm)

  detect_k<<<1, 64, 0, stream>>>((const unsigned int*)d_in[5], flag);
  cvtall_k<<<(IN_END + 255) / 256, 256, 0, stream>>>(ptrs, ws, flag);
  wcatT_k<<<2880, 256, 0, stream>>>(ws + OFF_WQ, ws + OFF_WK, ws + OFF_WV,
                                    ws + OFF_WQP, ws + OFF_WKP, ws + OFF_WVP, WcatT);
  wT_k<<<1920, 256, 0, stream>>>(ws + OFF_WO, WoT, FEATD, CSD);
  wT_k<<<576, 256, 0, stream>>>(ws + OFF_WT1, Wt1T, CSD, CSD);
  wT_k<<<576, 256, 0, stream>>>(ws + OFF_WT2, Wt2T, CSD, CSD);
  wT_k<<<576, 256, 0, stream>>>(ws + OFF_WT3, Wt3T, CSD, CSD);
  wreduce_k<<<24, 256, 0, stream>>>(ws + OFF_WPOST, ws + OFF_WRES, WpostR, WresR);
  mhc_k<<<BL, 64, 0, stream>>>(sF, ws + OFF_QUAT, ws + OFF_BPOST, ws + OFF_BRES, ws + OFF_ALPHA,
                               WpostR, WresR, hpost, rowsum, rotb);
  gemm_mfma_k<<<dim3(15, 32), 256, 0, stream>>>(sF, WcatT, nullptr, proj, BL, NPROJ, CSD, 0);
  assemble_k<<<128, 256, 0, stream>>>(proj, rotb, ws + OFF_TRANS, ws + OFF_Z1, ws + OFF_Z2,
                                      ws + OFF_WZQ, ws + OFF_WZK, ws + OFF_HEADW, Qb, Kb, Vtb);
  attn_k<<<dim3(16, 32), 256, 0, stream>>>(Qb, Kb, Vtb, ws + OFF_MASK, Oext);
  feat_k<<<128, 256, 0, stream>>>(Oext, rotb, ws + OFF_TRANS, featb);
  gemm_mfma_k<<<dim3(3, 32), 256, 0, stream>>>(featb, WoT, ws + OFF_BO, x1s1, BL, CSD, FEATD, 0);
  ln_k<<<BL, 64, 0, stream>>>(x1s1, sF, ws + OFF_LN1G, ws + OFF_LN1B, x1s1);                   // s1
  gemm_mfma_k<<<dim3(3, 32), 256, 0, stream>>>(x1s1, Wt1T, ws + OFF_BT1, t1b, BL, CSD, CSD, 1);
  gemm_mfma_k<<<dim3(3, 32), 256, 0, stream>>>(t1b, Wt2T, ws + OFF_BT2, t2b, BL, CSD, CSD, 1);
  gemm_mfma_k<<<dim3(3, 32), 256, 0, stream>>>(t2b, Wt3T, ws + OFF_BT3, x3, BL, CSD, CSD, 0);
  ln_k<<<BL, 64, 0, stream>>>(x3, x1s1, ws + OFF_LNTG, ws + OFF_LNTB, sipa);                   // s_ipa
  final_k<<<BL, 64, 0, stream>>>(sF, sipa, rotb, ws + OFF_TRANS, hpost, rowsum,
                                 ws + OFF_WBB, ws + OFF_BBB, flag, d_out);
}

// Round 6
// 542.443 us; speedup vs baseline: 2.0941x; 1.0023x over previous
//
#include <hip/hip_runtime.h>
#include <hip/hip_bf16.h>

typedef __hip_bfloat16 bf16;
typedef float f4v __attribute__((ext_vector_type(4)));
typedef short s8v __attribute__((ext_vector_type(8)));

#define CSD    384
#define LL     1024
#define NH     8
#define BL     4096        // B*L
#define NPROJ  1920
#define QDP    96          // 80 real ext-Q/K dims, padded to 96
#define VDP    160         // 152 real ext-V dims, padded to 160
#define FEATD  1280

// ---- fp32 input mirror layout (float offsets inside d_ws) ----
#define OFF_S      0
#define OFF_Z1     1572864
#define OFF_Z2     2621440
#define OFF_QUAT   4718592
#define OFF_TRANS  4734976
#define OFF_MASK   4747264
#define OFF_BPOST  4751360
#define OFF_BRES   4751376
#define OFF_WPOST  4751392
#define OFF_WRES   4757536
#define OFF_ALPHA  4782112
#define OFF_WQ     4782128
#define OFF_WK     4978736
#define OFF_WV     5175344
#define OFF_WQP    5371952
#define OFF_WKP    5408816
#define OFF_WVP    5445680
#define OFF_WZQ    5519408
#define OFF_WZK    5520432
#define OFF_HEADW  5521456
#define OFF_WO     5521472
#define OFF_BO     6012992
#define OFF_LN1G   6013376
#define OFF_LN1B   6013760
#define OFF_WT1    6014144
#define OFF_BT1    6161600
#define OFF_WT2    6161984
#define OFF_BT2    6309440
#define OFF_WT3    6309824
#define OFF_BT3    6457280
#define OFF_LNTG   6457664
#define OFF_LNTB   6458048
#define OFF_WBB    6458432
#define OFF_BBB    6460736
#define IN_END     6460752

// ---- scratch layout after the mirror (float offsets) ----
#define WS_FLAG    6460752
#define WS_WPOSTR  6460768      // 1,536
#define WS_WRESR   6462304      // 6,144
#define WS_HPOST   6468448      // 16,384
#define WS_ROWSUM  6484832      // 16,384
#define WS_ROTB    6501216      // 36,864
#define WS_WCATT   6538080      // bf16 Wcat^T [1920][384]  (368,640 f32 slots)
#define WS_PROJ    7275360      // 7,864,320 floats ; overlays: Oext, x1/s1, x3
#define WS_QB      15139680     // bf16 Q [32][1024][96]  (1,572,864 f32 slots)
#define WS_KB      16712544     // bf16 K [32][1024][96]  (1,572,864 f32 slots)
#define WS_VT      18285408     // bf16 V^T [32][160][1024] (2,621,440 f32 slots)
#define WS_WOT     20906848     // bf16 Wo^T [384][1280] (245,760 f32 slots)
#define WS_WT1T    21152608     // bf16 Wt1^T [384][384] (73,728)
#define WS_WT2T    21226336
#define WS_WT3T    21300064
#define WS_VROW    21373792     // bf16 V row-major [32][1024][160] (2,621,440 f32 slots)
// end: 23,995,232 floats = 96.0 MB

#define OUT_ROT 6291456
#define OUT_TR  6328320

#define NSEG 34

struct P36 { const void* p[36]; };

__device__ __forceinline__ float b2f(bf16 x) { return __bfloat162float(x); }

// float -> bf16 bits (round-to-nearest-even)
__device__ __forceinline__ short f2bs(float x) {
  unsigned u = __float_as_uint(x);
  u += 0x7FFFu + ((u >> 16) & 1u);
  return (short)(u >> 16);
}

__device__ __forceinline__ int packbf(float lo, float hi) {
  return (int)(unsigned short)f2bs(lo) | ((int)f2bs(hi) << 16);
}

__device__ __forceinline__ float wredf(float v) {
#pragma unroll
  for (int o = 1; o < 64; o <<= 1) v += __shfl_xor(v, o, 64);
  return v;
}

// ---------- dtype detect: mask is all-ones; bf16 pair = 0x3F803F80, fp32 = 0x3F800000 ----------
__global__ void detect_k(const unsigned int* __restrict__ mask_raw, int* __restrict__ flag) {
  if (threadIdx.x == 0 && blockIdx.x == 0) flag[0] = (mask_raw[0] == 0x3F803F80u) ? 1 : 0;
}

// ---------- convert ALL inputs into contiguous fp32 mirror ----------
__global__ __launch_bounds__(256) void cvtall_k(P36 ptrs, float* __restrict__ dst, const int* __restrict__ flagp) {
  const int i = blockIdx.x * 256 + threadIdx.x;
  if (i >= IN_END) return;
  const int flag = flagp[0];
  const int seg_src_t[NSEG] = {0,1,2,3,4,5,7,8,10,11,12,13,14,15,16,17,18,19,20,21,22,23,24,25,26,27,28,29,30,31,32,33,34,35};
  const int seg_dst_t[NSEG] = {OFF_S,OFF_Z1,OFF_Z2,OFF_QUAT,OFF_TRANS,OFF_MASK,OFF_BPOST,OFF_BRES,OFF_WPOST,OFF_WRES,
                               OFF_ALPHA,OFF_WQ,OFF_WK,OFF_WV,OFF_WQP,OFF_WKP,OFF_WVP,OFF_WZQ,OFF_WZK,OFF_HEADW,
                               OFF_WO,OFF_BO,OFF_LN1G,OFF_LN1B,OFF_WT1,OFF_BT1,OFF_WT2,OFF_BT2,OFF_WT3,OFF_BT3,
                               OFF_LNTG,OFF_LNTB,OFF_WBB,OFF_BBB};
  const int seg_cnt_t[NSEG] = {1572864,1048576,2097152,16384,12288,4096,4,16,6144,24576,
                               1,196608,196608,196608,36864,36864,73728,1024,1024,8,
                               491520,384,384,384,147456,384,147456,384,147456,384,
                               384,384,2304,6};
  int off = i, cnt = seg_cnt_t[0];
  const void* sp = ptrs.p[0];
#pragma unroll
  for (int k = 1; k < NSEG; k++) {
    if (i >= seg_dst_t[k]) { off = i - seg_dst_t[k]; cnt = seg_cnt_t[k]; sp = ptrs.p[seg_src_t[k]]; }
  }
  float v = 0.f;
  if (off < cnt) {
    v = flag ? b2f(((const bf16*)sp)[off]) : ((const float*)sp)[off];
  }
  dst[i] = v;
}

// ---------- build Wcat^T bf16 [1920][384] from fp32 mirror weights ----------
__global__ __launch_bounds__(256) void wcatT_k(const float* __restrict__ Wq, const float* __restrict__ Wk,
                                               const float* __restrict__ Wv, const float* __restrict__ Wqp,
                                               const float* __restrict__ Wkp, const float* __restrict__ Wvp,
                                               short* __restrict__ WcatT) {
  int i = blockIdx.x * 256 + threadIdx.x;    // i = k*1920 + n (coalesced reads)
  if (i >= CSD * NPROJ) return;
  int k = i / NPROJ, c = i % NPROJ;
  float v;
  if (c < 512)       v = Wq[k * 512 + c];
  else if (c < 1024) v = Wk[k * 512 + c - 512];
  else if (c < 1536) v = Wv[k * 512 + c - 1024];
  else if (c < 1632) v = Wqp[k * 96 + c - 1536];
  else if (c < 1728) v = Wkp[k * 96 + c - 1632];
  else               v = Wvp[k * 192 + c - 1728];
  WcatT[c * CSD + k] = f2bs(v);
}

// ---------- generic transpose fp32 [K][N] -> bf16 [N][K] ----------
__global__ __launch_bounds__(256) void wT_k(const float* __restrict__ W, short* __restrict__ Wt, int K, int N) {
  int i = blockIdx.x * 256 + threadIdx.x;    // i = k*N + n (coalesced reads)
  if (i >= K * N) return;
  int k = i / N, n = i % N;
  Wt[(size_t)n * K + k] = f2bs(W[i]);
}

// ---------- reduce W_post [1536,4]->[384,4], W_res [1536,16]->[384,16] ----------
__global__ __launch_bounds__(256) void wreduce_k(const float* __restrict__ Wpost, const float* __restrict__ Wres,
                                                 float* __restrict__ WpostR, float* __restrict__ WresR) {
  int i = blockIdx.x * 256 + threadIdx.x;
  if (i < CSD * 4) {
    int c = i >> 2, n = i & 3;
    float s = 0.f;
#pragma unroll
    for (int blk = 0; blk < 4; blk++) s += Wpost[(blk * CSD + c) * 4 + n];
    WpostR[i] = s;
  }
  if (i < CSD * 16) {
    int c = i >> 4, n = i & 15;
    float s = 0.f;
#pragma unroll
    for (int blk = 0; blk < 4; blk++) s += Wres[(blk * CSD + c) * 16 + n];
    WresR[i] = s;
  }
}

// ---------- per-residue: H_post, sinkhorn row-sums, quat->rot ----------
__global__ __launch_bounds__(64) void mhc_k(const float* __restrict__ sF, const float* __restrict__ quat,
                                            const float* __restrict__ bpost, const float* __restrict__ bres,
                                            const float* __restrict__ alpha_p, const float* __restrict__ WpostR,
                                            const float* __restrict__ WresR, float* __restrict__ hpost,
                                            float* __restrict__ rowsum, float* __restrict__ rotb) {
  const int bl = blockIdx.x, t = threadIdx.x;
  const float* sr = sF + (size_t)bl * CSD;
  float ssq = 0.f, dp[4] = {0.f, 0.f, 0.f, 0.f}, dr[16];
#pragma unroll
  for (int n = 0; n < 16; n++) dr[n] = 0.f;
#pragma unroll
  for (int e = 0; e < 6; e++) {
    const int c = t + e * 64;
    const float sv = sr[c];
    ssq = fmaf(sv, sv, ssq);
#pragma unroll
    for (int n = 0; n < 4; n++) dp[n] = fmaf(sv, WpostR[c * 4 + n], dp[n]);
#pragma unroll
    for (int n = 0; n < 16; n++) dr[n] = fmaf(sv, WresR[c * 16 + n], dr[n]);
  }
  ssq = wredf(ssq);
#pragma unroll
  for (int n = 0; n < 4; n++) dp[n] = wredf(dp[n]);
#pragma unroll
  for (int n = 0; n < 16; n++) dr[n] = wredf(dr[n]);
  const float alpha = alpha_p[0];
  const float invn = rsqrtf(ssq * (1.f / 384.f) + 1e-6f);
  if (t == 0) {
#pragma unroll
    for (int n = 0; n < 4; n++) {
      const float x = bpost[n] + alpha * invn * dp[n];
      hpost[bl * 4 + n] = 2.f / (1.f + __expf(-x));
    }
    float M[16];
    float mx = -1e30f;
#pragma unroll
    for (int k = 0; k < 16; k++) { M[k] = bres[k] + alpha * invn * dr[k]; mx = fmaxf(mx, M[k]); }
#pragma unroll
    for (int k = 0; k < 16; k++) M[k] = __expf(M[k] - mx);
    for (int it = 0; it < 20; it++) {
#pragma unroll
      for (int r = 0; r < 4; r++) {
        const float s4 = M[r * 4] + M[r * 4 + 1] + M[r * 4 + 2] + M[r * 4 + 3];
        const float iv = 1.f / (s4 + 1e-8f);
        M[r * 4] *= iv; M[r * 4 + 1] *= iv; M[r * 4 + 2] *= iv; M[r * 4 + 3] *= iv;
      }
#pragma unroll
      for (int c2 = 0; c2 < 4; c2++) {
        const float s4 = M[c2] + M[4 + c2] + M[8 + c2] + M[12 + c2];
        const float iv = 1.f / (s4 + 1e-8f);
        M[c2] *= iv; M[4 + c2] *= iv; M[8 + c2] *= iv; M[12 + c2] *= iv;
      }
    }
#pragma unroll
    for (int r = 0; r < 4; r++)
      rowsum[bl * 4 + r] = M[r * 4] + M[r * 4 + 1] + M[r * 4 + 2] + M[r * 4 + 3];
  }
  if (t == 1) {
    float w = quat[bl * 4 + 0], x = quat[bl * 4 + 1];
    float y = quat[bl * 4 + 2], z = quat[bl * 4 + 3];
    const float iq = rsqrtf(w * w + x * x + y * y + z * z + 1e-8f);
    w *= iq; x *= iq; y *= iq; z *= iq;
    float* R = rotb + (size_t)bl * 9;
    R[0] = 1.f - 2.f * (y * y + z * z); R[1] = 2.f * (x * y - w * z); R[2] = 2.f * (x * z + w * y);
    R[3] = 2.f * (x * y + w * z); R[4] = 1.f - 2.f * (x * x + z * z); R[5] = 2.f * (y * z - w * x);
    R[6] = 2.f * (x * z - w * y); R[7] = 2.f * (y * z + w * x); R[8] = 1.f - 2.f * (x * x + y * y);
  }
}

// ---------- MFMA bf16 GEMM: C[M,N](fp32) = A[M,K](fp32) @ Bt[N,K](bf16)^T (+bias)(+relu)
__global__ __launch_bounds__(256) void gemm_mfma_k(const float* __restrict__ A, const short* __restrict__ Bt,
                                                   const float* __restrict__ bias, float* __restrict__ C,
                                                   int M, int N, int K, int relu) {
  __shared__ __align__(16) short As[128 * 40];
  __shared__ __align__(16) short Bs[128 * 40];
  const int tid = threadIdx.x;
  const int wid = tid >> 6, lane = tid & 63;
  const int c15 = lane & 15, q = lane >> 4;
  const int bm = blockIdx.y, bn = blockIdx.x;
  const int m_wave = (wid & 1) * 64, n_wave = (wid >> 1) * 64;
  const float* Ab = A + (size_t)(bm * 128) * K;
  const short* Bb = Bt + (size_t)(bn * 128) * K;

  f4v acc[4][4];
#pragma unroll
  for (int mi = 0; mi < 4; mi++)
#pragma unroll
    for (int ni = 0; ni < 4; ni++) acc[mi][ni] = (f4v){0.f, 0.f, 0.f, 0.f};

  for (int k0 = 0; k0 < K; k0 += 32) {
    __syncthreads();
#pragma unroll
    for (int e = 0; e < 4; e++) {
      const int slot = tid + e * 256;
      const int m = slot >> 3, k4 = (slot & 7) * 4;
      const float4 a = *(const float4*)(Ab + (size_t)m * K + k0 + k4);
      short pk[4] = {f2bs(a.x), f2bs(a.y), f2bs(a.z), f2bs(a.w)};
      *(int2*)&As[m * 40 + k4] = *(const int2*)pk;
    }
#pragma unroll
    for (int e = 0; e < 2; e++) {
      const int slot = tid + e * 256;
      const int n = slot >> 2, k8 = (slot & 3) * 8;
      *(int4*)&Bs[n * 40 + k8] = *(const int4*)(Bb + (size_t)n * K + k0 + k8);
    }
    __syncthreads();
    s8v Af[4], Bf[4];
#pragma unroll
    for (int mi = 0; mi < 4; mi++) Af[mi] = *(const s8v*)&As[(m_wave + mi * 16 + c15) * 40 + q * 8];
#pragma unroll
    for (int ni = 0; ni < 4; ni++) Bf[ni] = *(const s8v*)&Bs[(n_wave + ni * 16 + c15) * 40 + q * 8];
#pragma unroll
    for (int mi = 0; mi < 4; mi++)
#pragma unroll
      for (int ni = 0; ni < 4; ni++)
        acc[mi][ni] = __builtin_amdgcn_mfma_f32_16x16x32_bf16(Af[mi], Bf[ni], acc[mi][ni], 0, 0, 0);
  }
#pragma unroll
  for (int mi = 0; mi < 4; mi++) {
#pragma unroll
    for (int r = 0; r < 4; r++) {
      const int row = bm * 128 + m_wave + mi * 16 + q * 4 + r;
      float* Cr = C + (size_t)row * N + bn * 128 + n_wave;
#pragma unroll
      for (int ni = 0; ni < 4; ni++) {
        const int col = bn * 128 + n_wave + ni * 16 + c15;
        float v = acc[mi][ni][r];
        if (bias != nullptr) v += bias[col];
        if (relu) v = fmaxf(v, 0.f);
        Cr[ni * 16 + c15] = v;
      }
    }
  }
}

// ---------- assemble extended Q/K (bf16 [bh][L][96]) and V row-major (bf16 [bh][L][160]), packed int4 stores ----------
__global__ __launch_bounds__(256) void assemble_k(const float* __restrict__ proj, const float* __restrict__ rotb,
                                                  const float* __restrict__ trans, const float* __restrict__ z1,
                                                  const float* __restrict__ z2, const float* __restrict__ Wzq,
                                                  const float* __restrict__ Wzk, const float* __restrict__ headw,
                                                  int* __restrict__ Qo4, int* __restrict__ Ko4,
                                                  int* __restrict__ Vr4) {
  const int idx = blockIdx.x * 256 + threadIdx.x;  // < 32768
  const int h = idx & 7, bl = idx >> 3;
  const float* pr = proj + (size_t)bl * NPROJ;
  const float* R = rotb + (size_t)bl * 9;
  const float txx = trans[bl * 3 + 0], tyy = trans[bl * 3 + 1], tzz = trans[bl * 3 + 2];
  float gamma;
  { const float w = headw[h]; gamma = (w > 20.f) ? w : log1pf(__expf(w)); }
  const float wL = 0.57735026918962576f;  // sqrt(1/3)
  const float wC = 0.23570226039551584f;  // sqrt(2/(9*4))
  const float ch = wL * wC * 0.5f * gamma;
  const float qscale = wL * 0.125f;       // wL / sqrt(64)

  float zq0 = 0.f, zq1 = 0.f, zk0 = 0.f, zk1 = 0.f;
  const float* z1r = z1 + (size_t)bl * 256;
  for (int zz = 0; zz < 128; zz++) {
    const float wq = Wzq[zz * 8 + h], wk = Wzk[zz * 8 + h];
    const float a0 = z1r[zz], a1 = z1r[128 + zz];
    zq0 = fmaf(a0, wq, zq0); zq1 = fmaf(a1, wq, zq1);
    zk0 = fmaf(a0, wk, zk0); zk1 = fmaf(a1, wk, zk1);
  }
  const int b = bl >> 10, l = bl & 1023;
  const size_t row = (size_t)(b * NH + h) * LL + l;
  int* Qo = Qo4 + row * 48;   // 96 shorts
  int* Ko = Ko4 + row * 48;
  int* Vo = Vr4 + row * 80;   // 160 shorts
  // cols 0..63 (q,k scaled; v plain)
#pragma unroll
  for (int g = 0; g < 8; g++) {
    int4 qi, ki, vi;
#pragma unroll
    for (int t2 = 0; t2 < 4; t2++) {
      const int c = g * 8 + t2 * 2;
      ((int*)&qi)[t2] = packbf(pr[h * 64 + c] * qscale, pr[h * 64 + c + 1] * qscale);
      ((int*)&ki)[t2] = packbf(pr[512 + h * 64 + c], pr[512 + h * 64 + c + 1]);
      ((int*)&vi)[t2] = packbf(pr[1024 + h * 64 + c], pr[1024 + h * 64 + c + 1]);
    }
    ((int4*)Qo)[g] = qi; ((int4*)Ko)[g] = ki; ((int4*)Vo)[g] = vi;
  }
  // Q/K tail cols 64..79
  float qt16[16], kt16[16];
  qt16[0] = wL * zq0; qt16[1] = wL * zq1;
  kt16[0] = zk0; kt16[1] = zk1;
  float qn = 0.f, kn = 0.f;
#pragma unroll
  for (int p = 0; p < 4; p++) {
    const float* pl = pr + 1536 + h * 12 + p * 3;
    float gx = R[0] * pl[0] + R[1] * pl[1] + R[2] * pl[2] + txx;
    float gy = R[3] * pl[0] + R[4] * pl[1] + R[5] * pl[2] + tyy;
    float gz = R[6] * pl[0] + R[7] * pl[1] + R[8] * pl[2] + tzz;
    qn += gx * gx + gy * gy + gz * gz;
    qt16[2 + p * 3 + 0] = 2.f * ch * gx; qt16[2 + p * 3 + 1] = 2.f * ch * gy; qt16[2 + p * 3 + 2] = 2.f * ch * gz;
    const float* pk = pr + 1632 + h * 12 + p * 3;
    gx = R[0] * pk[0] + R[1] * pk[1] + R[2] * pk[2] + txx;
    gy = R[3] * pk[0] + R[4] * pk[1] + R[5] * pk[2] + tyy;
    gz = R[6] * pk[0] + R[7] * pk[1] + R[8] * pk[2] + tzz;
    kn += gx * gx + gy * gy + gz * gz;
    kt16[2 + p * 3 + 0] = gx; kt16[2 + p * 3 + 1] = gy; kt16[2 + p * 3 + 2] = gz;
  }
  qt16[14] = -ch * qn; qt16[15] = 1.f;
  kt16[14] = 1.f;      kt16[15] = -ch * kn;
#pragma unroll
  for (int g = 0; g < 2; g++) {
    int4 qi, ki;
#pragma unroll
    for (int t2 = 0; t2 < 4; t2++) {
      const int c = g * 8 + t2 * 2;
      ((int*)&qi)[t2] = packbf(qt16[c], qt16[c + 1]);
      ((int*)&ki)[t2] = packbf(kt16[c], kt16[c + 1]);
    }
    ((int4*)Qo)[8 + g] = qi; ((int4*)Ko)[8 + g] = ki;
  }
  int4 z4; z4.x = 0; z4.y = 0; z4.z = 0; z4.w = 0;
  ((int4*)Qo)[10] = z4; ((int4*)Qo)[11] = z4;
  ((int4*)Ko)[10] = z4; ((int4*)Ko)[11] = z4;
  // V cols 64..87 (points)
  float vt24[24];
#pragma unroll
  for (int p = 0; p < 8; p++) {
    const float* pv = pr + 1728 + h * 24 + p * 3;
    vt24[p * 3 + 0] = R[0] * pv[0] + R[1] * pv[1] + R[2] * pv[2] + txx;
    vt24[p * 3 + 1] = R[3] * pv[0] + R[4] * pv[1] + R[5] * pv[2] + tyy;
    vt24[p * 3 + 2] = R[6] * pv[0] + R[7] * pv[1] + R[8] * pv[2] + tzz;
  }
#pragma unroll
  for (int g = 0; g < 3; g++) {
    int4 vi;
#pragma unroll
    for (int t2 = 0; t2 < 4; t2++) {
      const int c = g * 8 + t2 * 2;
      ((int*)&vi)[t2] = packbf(vt24[c], vt24[c + 1]);
    }
    ((int4*)Vo)[8 + g] = vi;
  }
  // V cols 88..151 (z2)
  const float* z2r = z2 + ((size_t)bl * NH + h) * 64;
#pragma unroll
  for (int g = 0; g < 8; g++) {
    int4 vi;
#pragma unroll
    for (int t2 = 0; t2 < 4; t2++) {
      const int c = g * 8 + t2 * 2;
      ((int*)&vi)[t2] = packbf(z2r[c], z2r[c + 1]);
    }
    ((int4*)Vo)[11 + g] = vi;
  }
  ((int4*)Vo)[19] = z4;  // cols 152..159
}

// ---------- transpose V row-major [bh][L][160] -> V^T [bh][160][L] via LDS tile ----------
__global__ __launch_bounds__(256) void vtrans_k(const short* __restrict__ Vrow, short* __restrict__ Vtb) {
  __shared__ __align__(16) short T[64 * 168];
  const int tid = threadIdx.x;
  const int bh = blockIdx.y;
  const int l0 = blockIdx.x * 64;
  const short* src = Vrow + (size_t)bh * LL * VDP + (size_t)l0 * VDP;
  for (int u = tid; u < 1280; u += 256) {
    const int ll = u / 20, j = u % 20;
    *(int4*)&T[ll * 168 + j * 8] = *(const int4*)(src + (size_t)ll * VDP + j * 8);
  }
  __syncthreads();
  short* dst = Vtb + (size_t)bh * VDP * LL + l0;
  for (int u = tid; u < 1280; u += 256) {      // FIX: was u<640/seg&3 — only half the rows stored
    const int c = u >> 3, seg = u & 7;
    short tmp[8];
#pragma unroll
    for (int e = 0; e < 8; e++) tmp[e] = T[(seg * 8 + e) * 168 + c];
    *(int4*)(dst + (size_t)c * LL + seg * 8) = *(const int4*)tmp;
  }
}

// ---------- MFMA flash attention v2: 8 waves, intra-block j-split (halves), 64 q-rows/block ----------
__global__ __launch_bounds__(512, 4) void attn_k(const short* __restrict__ Qb, const short* __restrict__ Kb,
                                                 const short* __restrict__ Vtb, const float* __restrict__ maskF,
                                                 float* __restrict__ Oext) {
  __shared__ __align__(16) short smem[24704];   // 49,408 B
  short* Ks = smem;                    // [2][32][104]
  short* Vs = smem + 6656;             // [2][160][40]
  short* Ps = smem + 19456;            // [8][16][40]
  float* Msl = (float*)(smem + 24576); // [2][32]
  const int tid = threadIdx.x;
  const int wid = tid >> 6, lane = tid & 63;
  const int c15 = lane & 15, q = lane >> 4;
  const int blk = blockIdx.x;
  const int bh = blk & 31, qt = blk >> 5;       // same-bh blocks share blk%8 -> same XCD (L2 reuse)
  const int b = bh >> 3, h = bh & 7;
  const int half = wid >> 2, mw = wid & 3;
  const int i0 = qt * 64 + mw * 16;

  s8v Qa[3];
  const short* Qrow = Qb + ((size_t)bh * LL + i0 + c15) * QDP;
#pragma unroll
  for (int kc = 0; kc < 3; kc++) Qa[kc] = *(const s8v*)(Qrow + kc * 32 + q * 8);

  f4v Of[10];
#pragma unroll
  for (int vt = 0; vt < 10; vt++) Of[vt] = (f4v){0.f, 0.f, 0.f, 0.f};
  float mold[4] = {-1e30f, -1e30f, -1e30f, -1e30f};
  float lsum[4] = {0.f, 0.f, 0.f, 0.f};

  const short* Kbase = Kb + (size_t)bh * LL * QDP;
  const short* Vbase = Vtb + (size_t)bh * VDP * LL;
  short* Ksl = Ks + half * 3328;
  short* Vsl = Vs + half * 6400;
  short* Pl = Ps + wid * 640;
  const float* Msw = Msl + half * 32;

  for (int jt = 0; jt < 16; jt++) {
    const int j0 = jt * 32;
    __syncthreads();
    for (int u = tid; u < 768; u += 512) {
      const int hs = u / 384, v2 = u - hs * 384;
      const int rr = v2 / 12, cc = v2 % 12;
      *(int4*)&Ks[hs * 3328 + rr * 104 + cc * 8] =
          *(const int4*)(Kbase + (size_t)(hs * 512 + j0 + rr) * QDP + cc * 8);
    }
    for (int u = tid; u < 1280; u += 512) {
      const int hs = u / 640, v2 = u - hs * 640;
      const int cc = v2 >> 2, part = v2 & 3;
      *(int4*)&Vs[hs * 6400 + cc * 40 + part * 8] =
          *(const int4*)(Vbase + (size_t)cc * LL + hs * 512 + j0 + part * 8);
    }
    if (tid < 64) Msl[tid] = maskF[b * LL + (tid >> 5) * 512 + j0 + (tid & 31)];
    __syncthreads();

    f4v Sf0 = (f4v){0.f, 0.f, 0.f, 0.f}, Sf1 = (f4v){0.f, 0.f, 0.f, 0.f};
#pragma unroll
    for (int kc = 0; kc < 3; kc++) {
      const s8v K0 = *(const s8v*)&Ksl[c15 * 104 + kc * 32 + q * 8];
      const s8v K1 = *(const s8v*)&Ksl[(16 + c15) * 104 + kc * 32 + q * 8];
      Sf0 = __builtin_amdgcn_mfma_f32_16x16x32_bf16(Qa[kc], K0, Sf0, 0, 0, 0);
      Sf1 = __builtin_amdgcn_mfma_f32_16x16x32_bf16(Qa[kc], K1, Sf1, 0, 0, 0);
    }
    const float mv0 = Msw[c15], mv1 = Msw[16 + c15];
    float lg0[4], lg1[4], tm[4], p0[4], p1[4];
#pragma unroll
    for (int r = 0; r < 4; r++) {
      lg0[r] = (mv0 > 0.f) ? Sf0[r] : -1e9f;
      lg1[r] = (mv1 > 0.f) ? Sf1[r] : -1e9f;
      tm[r] = fmaxf(lg0[r], lg1[r]);
    }
#pragma unroll
    for (int r = 0; r < 4; r++) {
      tm[r] = fmaxf(tm[r], __shfl_xor(tm[r], 1, 64));
      tm[r] = fmaxf(tm[r], __shfl_xor(tm[r], 2, 64));
      tm[r] = fmaxf(tm[r], __shfl_xor(tm[r], 4, 64));
      tm[r] = fmaxf(tm[r], __shfl_xor(tm[r], 8, 64));
    }
    const bool need = (tm[0] > mold[0]) | (tm[1] > mold[1]) | (tm[2] > mold[2]) | (tm[3] > mold[3]);
    if (__any(need)) {
      float al[4];
#pragma unroll
      for (int r = 0; r < 4; r++) {
        const float mn = fmaxf(mold[r], tm[r]);
        al[r] = __expf(mold[r] - mn);
        mold[r] = mn;
        p0[r] = __expf(lg0[r] - mn);
        p1[r] = __expf(lg1[r] - mn);
        lsum[r] = lsum[r] * al[r] + p0[r] + p1[r];
      }
#pragma unroll
      for (int vt = 0; vt < 10; vt++) {
#pragma unroll
        for (int r = 0; r < 4; r++) Of[vt][r] *= al[r];
      }
    } else {
#pragma unroll
      for (int r = 0; r < 4; r++) {
        p0[r] = __expf(lg0[r] - mold[r]);
        p1[r] = __expf(lg1[r] - mold[r]);
        lsum[r] += p0[r] + p1[r];
      }
    }
#pragma unroll
    for (int r = 0; r < 4; r++) {
      Pl[(q * 4 + r) * 40 + c15] = f2bs(p0[r]);
      Pl[(q * 4 + r) * 40 + 16 + c15] = f2bs(p1[r]);
    }
    const s8v Pa = *(const s8v*)&Pl[c15 * 40 + q * 8];
#pragma unroll
    for (int vt = 0; vt < 10; vt++) {
      const s8v Vf = *(const s8v*)&Vsl[(vt * 16 + c15) * 40 + q * 8];
      Of[vt] = __builtin_amdgcn_mfma_f32_16x16x32_bf16(Pa, Vf, Of[vt], 0, 0, 0);
    }
  }
  // reduce lsum across the 16 c15 lanes of each quad
#pragma unroll
  for (int r = 0; r < 4; r++) {
    lsum[r] += __shfl_xor(lsum[r], 1, 64);
    lsum[r] += __shfl_xor(lsum[r], 2, 64);
    lsum[r] += __shfl_xor(lsum[r], 4, 64);
    lsum[r] += __shfl_xor(lsum[r], 8, 64);
  }
  // merge halves through LDS (reuse tile space)
  float* Obuf = (float*)smem;            // [4][16][160]
  float* Mbuf = (float*)(smem + 20480);  // [64]
  float* Lbuf = Mbuf + 64;               // [64]
  __syncthreads();
  if (half == 1) {
#pragma unroll
    for (int r = 0; r < 4; r++) {
      const int rowi = mw * 16 + q * 4 + r;
#pragma unroll
      for (int vt = 0; vt < 10; vt++) Obuf[rowi * 160 + vt * 16 + c15] = Of[vt][r];
      if (c15 == 0) { Mbuf[rowi] = mold[r]; Lbuf[rowi] = lsum[r]; }
    }
  }
  __syncthreads();
  if (half == 0) {
#pragma unroll
    for (int r = 0; r < 4; r++) {
      const int rowi = mw * 16 + q * 4 + r;
      const float m2 = Mbuf[rowi], l2 = Lbuf[rowi];
      const float mx = fmaxf(mold[r], m2);
      const float a1 = __expf(mold[r] - mx), a2 = __expf(m2 - mx);
      const float inv = 1.f / (lsum[r] * a1 + l2 * a2);
      const int i = i0 + q * 4 + r;
      float* Or = Oext + ((size_t)(b * LL + i) * NH + h) * VDP;
#pragma unroll
      for (int vt = 0; vt < 10; vt++)
        Or[vt * 16 + c15] = (Of[vt][r] * a1 + Obuf[rowi * 160 + vt * 16 + c15] * a2) * inv;
    }
  }
}

// ---------- feat assembly: local-frame transform + norms (thread per (b,l,h)) ----------
__global__ __launch_bounds__(256) void feat_k(const float* __restrict__ Oext, const float* __restrict__ rotb,
                                              const float* __restrict__ trans, float* __restrict__ feat) {
  const int idx = blockIdx.x * 256 + threadIdx.x;
  const int h = idx & 7, bl = idx >> 3;
  const float* O = Oext + (size_t)(bl * 8 + h) * VDP;
  float* f = feat + (size_t)bl * FEATD;
  for (int c = 0; c < 64; c++) f[h * 64 + c] = O[c];
  const float* R = rotb + (size_t)bl * 9;
  const float txx = trans[bl * 3 + 0], tyy = trans[bl * 3 + 1], tzz = trans[bl * 3 + 2];
#pragma unroll
  for (int p = 0; p < 8; p++) {
    const float dx = O[64 + p * 3 + 0] - txx;
    const float dy = O[64 + p * 3 + 1] - tyy;
    const float dz = O[64 + p * 3 + 2] - tzz;
    const float lx = R[0] * dx + R[3] * dy + R[6] * dz;   // R^T * diff
    const float ly = R[1] * dx + R[4] * dy + R[7] * dz;
    const float lz = R[2] * dx + R[5] * dy + R[8] * dz;
    f[512 + h * 24 + p * 3 + 0] = lx;
    f[512 + h * 24 + p * 3 + 1] = ly;
    f[512 + h * 24 + p * 3 + 2] = lz;
    f[704 + h * 8 + p] = sqrtf(lx * lx + ly * ly + lz * lz + 1e-8f);
  }
  for (int c = 0; c < 64; c++) f[768 + h * 64 + c] = O[88 + c];
}

// ---------- LayerNorm(x + resid) (one wave per row) ----------
__global__ __launch_bounds__(64) void ln_k(const float* __restrict__ x, const float* __restrict__ resid,
                                           const float* __restrict__ g, const float* __restrict__ bta,
                                           float* __restrict__ out) {
  const int row = blockIdx.x, t = threadIdx.x;
  const float* xr = x + (size_t)row * CSD;
  const float* rr = resid + (size_t)row * CSD;
  float v[6];
  float s = 0.f;
#pragma unroll
  for (int e = 0; e < 6; e++) {
    const int c = t + e * 64;
    v[e] = xr[c] + rr[c];
    s += v[e];
  }
  s = wredf(s);
  const float mu = s * (1.f / 384.f);
  float var = 0.f;
#pragma unroll
  for (int e = 0; e < 6; e++) { const float d = v[e] - mu; var = fmaf(d, d, var); }
  var = wredf(var) * (1.f / 384.f);
  const float inv = rsqrtf(var + 1e-5f);
#pragma unroll
  for (int e = 0; e < 6; e++) {
    const int c = t + e * 64;
    out[(size_t)row * CSD + c] = (v[e] - mu) * inv * g[c] + bta[c];
  }
}

// ---------- final: backbone update + mHC combine; writes output per dtype flag ----------
__global__ __launch_bounds__(64) void final_k(const float* __restrict__ sF, const float* __restrict__ sipa,
                                              const float* __restrict__ rotb, const float* __restrict__ trans,
                                              const float* __restrict__ hpost, const float* __restrict__ rowsum,
                                              const float* __restrict__ Wbb, const float* __restrict__ bbb,
                                              const int* __restrict__ flagp, void* __restrict__ outv) {
  const int bl = blockIdx.x, t = threadIdx.x;
  const int flag = flagp[0];
  bf16* outb = (bf16*)outv;
  float* outf = (float*)outv;
  const float* si = sipa + (size_t)bl * CSD;
  float d6[6] = {0.f, 0.f, 0.f, 0.f, 0.f, 0.f};
#pragma unroll
  for (int e = 0; e < 6; e++) {
    const int c = t + e * 64;
    const float v = si[c];
#pragma unroll
    for (int u = 0; u < 6; u++) d6[u] = fmaf(v, Wbb[c * 6 + u], d6[u]);
  }
#pragma unroll
  for (int u = 0; u < 6; u++) d6[u] = wredf(d6[u]);
  float upd[6];
#pragma unroll
  for (int u = 0; u < 6; u++) upd[u] = d6[u] + bbb[u];
  const float* R = rotb + (size_t)bl * 9;
  if (t == 0) {
    float w = 1.f, x = upd[0], y = upd[1], z = upd[2];
    const float iq = rsqrtf(w * w + x * x + y * y + z * z + 1e-8f);
    w *= iq; x *= iq; y *= iq; z *= iq;
    const float Ru[9] = {1.f - 2.f * (y * y + z * z), 2.f * (x * y - w * z), 2.f * (x * z + w * y),
                         2.f * (x * y + w * z), 1.f - 2.f * (x * x + z * z), 2.f * (y * z - w * x),
                         2.f * (x * z - w * y), 2.f * (y * z + w * x), 1.f - 2.f * (x * x + y * y)};
#pragma unroll
    for (int i = 0; i < 3; i++)
#pragma unroll
      for (int j = 0; j < 3; j++) {
        const float rv = R[i * 3 + 0] * Ru[0 + j] + R[i * 3 + 1] * Ru[3 + j] + R[i * 3 + 2] * Ru[6 + j];
        const size_t o = OUT_ROT + (size_t)bl * 9 + i * 3 + j;
        if (flag) outb[o] = __float2bfloat16(rv); else outf[o] = rv;
      }
#pragma unroll
    for (int i = 0; i < 3; i++) {
      const float tv = R[i * 3 + 0] * upd[3] + R[i * 3 + 1] * upd[4] + R[i * 3 + 2] * upd[5] + trans[bl * 3 + i];
      const size_t o = OUT_TR + (size_t)bl * 3 + i;
      if (flag) outb[o] = __float2bfloat16(tv); else outf[o] = tv;
    }
  }
  const float hp0 = hpost[bl * 4 + 0], hp1 = hpost[bl * 4 + 1], hp2 = hpost[bl * 4 + 2], hp3 = hpost[bl * 4 + 3];
  const float rs0 = rowsum[bl * 4 + 0], rs1 = rowsum[bl * 4 + 1], rs2 = rowsum[bl * 4 + 2], rs3 = rowsum[bl * 4 + 3];
  const float* sr = sF + (size_t)bl * CSD;
#pragma unroll
  for (int e = 0; e < 6; e++) {
    const int c = t + e * 64;
    const float sv = sr[c], sp = si[c];
    const size_t base = (size_t)bl * 4 * CSD + c;
    const float o0 = rs0 * sv + hp0 * sp;
    const float o1 = rs1 * sv + hp1 * sp;
    const float o2 = rs2 * sv + hp2 * sp;
    const float o3 = rs3 * sv + hp3 * sp;
    if (flag) {
      outb[base + 0 * CSD] = __float2bfloat16(o0);
      outb[base + 1 * CSD] = __float2bfloat16(o1);
      outb[base + 2 * CSD] = __float2bfloat16(o2);
      outb[base + 3 * CSD] = __float2bfloat16(o3);
    } else {
      outf[base + 0 * CSD] = o0;
      outf[base + 1 * CSD] = o1;
      outf[base + 2 * CSD] = o2;
      outf[base + 3 * CSD] = o3;
    }
  }
}

extern "C" void kernel_launch(void* const* d_in, const int* in_sizes, int n_in,
                              void* d_out, int out_size, void* d_ws, size_t ws_size,
                              hipStream_t stream) {
  float* ws = (float*)d_ws;
  int* flag = (int*)(ws + WS_FLAG);

  P36 ptrs;
  for (int i = 0; i < 36; i++) ptrs.p[i] = d_in[i];

  float* sF     = ws + OFF_S;
  float* WpostR = ws + WS_WPOSTR;
  float* WresR  = ws + WS_WRESR;
  float* hpost  = ws + WS_HPOST;
  float* rowsum = ws + WS_ROWSUM;
  float* rotb   = ws + WS_ROTB;
  short* WcatT  = (short*)(ws + WS_WCATT);
  short* WoT    = (short*)(ws + WS_WOT);
  short* Wt1T   = (short*)(ws + WS_WT1T);
  short* Wt2T   = (short*)(ws + WS_WT2T);
  short* Wt3T   = (short*)(ws + WS_WT3T);
  float* proj   = ws + WS_PROJ;
  short* Qb     = (short*)(ws + WS_QB);
  short* Kb     = (short*)(ws + WS_KB);
  short* Vtb    = (short*)(ws + WS_VT);
  short* Vrow   = (short*)(ws + WS_VROW);
  float* Oext   = ws + WS_PROJ;               // overlay (proj dead after assemble)
  float* featb  = ws + WS_QB;                 // overlay (Q/K/V^T dead after attn)
  float* x1s1   = ws + WS_PROJ;               // overlay (Oext dead after feat_k)
  float* t1b    = ws + WS_QB;                 // overlay (feat dead after Wo gemm)
  float* t2b    = ws + WS_KB;                 // overlay (disjoint from t1)
  float* x3     = ws + WS_PROJ + 1572864;     // s1 at WS_PROJ stays alive
  float* sipa   = ws + WS_KB;                 // overlay (t2 dead after x3 gemm)

  detect_k<<<1, 64, 0, stream>>>((const unsigned int*)d_in[5], flag);
  cvtall_k<<<(IN_END + 255) / 256, 256, 0, stream>>>(ptrs, ws, flag);
  wcatT_k<<<2880, 256, 0, stream>>>(ws + OFF_WQ, ws + OFF_WK, ws + OFF_WV,
                                    ws + OFF_WQP, ws + OFF_WKP, ws + OFF_WVP, WcatT);
  wT_k<<<1920, 256, 0, stream>>>(ws + OFF_WO, WoT, FEATD, CSD);
  wT_k<<<576, 256, 0, stream>>>(ws + OFF_WT1, Wt1T, CSD, CSD);
  wT_k<<<576, 256, 0, stream>>>(ws + OFF_WT2, Wt2T, CSD, CSD);
  wT_k<<<576, 256, 0, stream>>>(ws + OFF_WT3, Wt3T, CSD, CSD);
  wreduce_k<<<24, 256, 0, stream>>>(ws + OFF_WPOST, ws + OFF_WRES, WpostR, WresR);
  mhc_k<<<BL, 64, 0, stream>>>(sF, ws + OFF_QUAT, ws + OFF_BPOST, ws + OFF_BRES, ws + OFF_ALPHA,
                               WpostR, WresR, hpost, rowsum, rotb);
  gemm_mfma_k<<<dim3(15, 32), 256, 0, stream>>>(sF, WcatT, nullptr, proj, BL, NPROJ, CSD, 0);
  assemble_k<<<128, 256, 0, stream>>>(proj, rotb, ws + OFF_TRANS, ws + OFF_Z1, ws + OFF_Z2,
                                      ws + OFF_WZQ, ws + OFF_WZK, ws + OFF_HEADW,
                                      (int*)Qb, (int*)Kb, (int*)Vrow);
  vtrans_k<<<dim3(16, 32), 256, 0, stream>>>(Vrow, Vtb);
  attn_k<<<512, 512, 0, stream>>>(Qb, Kb, Vtb, ws + OFF_MASK, Oext);
  feat_k<<<128, 256, 0, stream>>>(Oext, rotb, ws + OFF_TRANS, featb);
  gemm_mfma_k<<<dim3(3, 32), 256, 0, stream>>>(featb, WoT, ws + OFF_BO, x1s1, BL, CSD, FEATD, 0);
  ln_k<<<BL, 64, 0, stream>>>(x1s1, sF, ws + OFF_LN1G, ws + OFF_LN1B, x1s1);                   // s1
  gemm_mfma_k<<<dim3(3, 32), 256, 0, stream>>>(x1s1, Wt1T, ws + OFF_BT1, t1b, BL, CSD, CSD, 1);
  gemm_mfma_k<<<dim3(3, 32), 256, 0, stream>>>(t1b, Wt2T, ws + OFF_BT2, t2b, BL, CSD, CSD, 1);
  gemm_mfma_k<<<dim3(3, 32), 256, 0, stream>>>(t2b, Wt3T, ws + OFF_BT3, x3, BL, CSD, CSD, 0);
  ln_k<<<BL, 64, 0, stream>>>(x3, x1s1, ws + OFF_LNTG, ws + OFF_LNTB, sipa);                   // s_ipa
  final_k<<<BL, 64, 0, stream>>>(sF, sipa, rotb, ws + OFF_TRANS, hpost, rowsum,
                                 ws + OFF_WBB, ws + OFF_BBB, flag, d_out);
}